// Round 3
// baseline (379.529 us; speedup 1.0000x reference)
//
#include <hip/hip_runtime.h>
#include <stdint.h>

#define B_ 2
#define T_ 1024
#define E_ 128
#define H_ 8
#define KMIX 8
#define NPTS_ 64
#define HID_ 64
#define NCONTRIB (B_ * T_ * NPTS_)   // 131072

// JAX threefry_partitionable default (JAX >= 0.4.36). Flip to 0 for legacy stream.
#define PARTITIONABLE 1

// ---------------- threefry2x32 (JAX/Random123) ----------------
__device__ __forceinline__ void tf2x32(uint32_t k0, uint32_t k1,
                                       uint32_t x0, uint32_t x1,
                                       uint32_t& o0, uint32_t& o1) {
  uint32_t ks2 = k0 ^ k1 ^ 0x1BD11BDAu;
  x0 += k0; x1 += k1;
#define RND(r) { x0 += x1; x1 = (x1 << (r)) | (x1 >> (32 - (r))); x1 ^= x0; }
  RND(13) RND(15) RND(26) RND(6)
  x0 += k1;  x1 += ks2 + 1u;
  RND(17) RND(29) RND(16) RND(24)
  x0 += ks2; x1 += k0 + 2u;
  RND(13) RND(15) RND(26) RND(6)
  x0 += k0;  x1 += k1 + 3u;
  RND(17) RND(29) RND(16) RND(24)
  x0 += k1;  x1 += ks2 + 4u;
  RND(13) RND(15) RND(26) RND(6)
  x0 += ks2; x1 += k0 + 5u;
#undef RND
  o0 = x0; o1 = x1;
}

#if PARTITIONABLE
// split(key)[i] = threefry(key, (0, i)) -> both words form the new key.
// random_bits(key,32,shape)[f] = o0 ^ o1 of threefry(key, (0, f)).   <-- XOR, per jax/_src/prng.py
__device__ __forceinline__ void derive_lower_key(int which, uint32_t& k0, uint32_t& k1) {
  // which: 0 -> kg (glob), 1 -> kn (loc). Returns k2 (lower key) of randint's internal split.
  uint32_t a0, a1;
  tf2x32(0u, 1u, 0u, (uint32_t)which, a0, a1);      // split(key(1))[which]
  tf2x32(a0, a1, 0u, 1u, k0, k1);                   // split(that)[1] = lower key
}
__device__ __forceinline__ uint32_t rand_bits32(uint32_t k0, uint32_t k1, uint32_t f) {
  uint32_t o0, o1;
  tf2x32(k0, k1, 0u, f, o0, o1);
  return o0 ^ o1;                                   // partitionable 32-bit draw
}
#else
// legacy (non-partitionable) threefry stream
__device__ __forceinline__ void split2_legacy(uint32_t k0, uint32_t k1,
                                              uint32_t& a0, uint32_t& a1,
                                              uint32_t& b0, uint32_t& b1) {
  uint32_t y00, y10, y01, y11;
  tf2x32(k0, k1, 0u, 2u, y00, y10);
  tf2x32(k0, k1, 1u, 3u, y01, y11);
  a0 = y00; a1 = y01; b0 = y10; b1 = y11;
}
__device__ __forceinline__ void derive_lower_key(int which, uint32_t& k0, uint32_t& k1) {
  uint32_t g0, g1, n0, n1;
  split2_legacy(0u, 1u, g0, g1, n0, n1);
  uint32_t s0 = which ? n0 : g0, s1 = which ? n1 : g1;
  uint32_t j0, j1;
  split2_legacy(s0, s1, j0, j1, k0, k1);            // lower key = second
  (void)j0; (void)j1;
}
__device__ __forceinline__ uint32_t rand_bits32(uint32_t k0, uint32_t k1, uint32_t f) {
  // total draw size 65536, half = 32768
  uint32_t o0, o1;
  if (f < 32768u) { tf2x32(k0, k1, f, f + 32768u, o0, o1); return o0; }
  tf2x32(k0, k1, f - 32768u, f, o0, o1); return o1;
}
#endif

// ---------------- kernel 1: projection GEMM  C = x(2048x128) @ W(128x1024) ----------------
// stores permuted to [b][h][t][e], scaled.
__global__ __launch_bounds__(256)
void proj_kernel(const float* __restrict__ A, const float* __restrict__ W,
                 float* __restrict__ out, float scale) {
  __shared__ float As[64][65];
  __shared__ float Bs[64][68];
  int tid = threadIdx.x;
  int tm = tid >> 4, tn = tid & 15;
  int row0 = blockIdx.x * 64;
  int col0 = blockIdx.y * 64;
  float acc[4][4] = {};
  for (int kk = 0; kk < 128; kk += 64) {
#pragma unroll
    for (int l = 0; l < 4; ++l) {
      int idx = tid + l * 256;
      int r = idx >> 4, c4 = idx & 15;
      float4 v = *(const float4*)(A + (size_t)(row0 + r) * 128 + kk + c4 * 4);
      As[r][c4 * 4 + 0] = v.x; As[r][c4 * 4 + 1] = v.y;
      As[r][c4 * 4 + 2] = v.z; As[r][c4 * 4 + 3] = v.w;
    }
#pragma unroll
    for (int l = 0; l < 4; ++l) {
      int idx = tid + l * 256;
      int r = idx >> 4, c4 = idx & 15;
      float4 v = *(const float4*)(W + (size_t)(kk + r) * 1024 + col0 + c4 * 4);
      Bs[r][c4 * 4 + 0] = v.x; Bs[r][c4 * 4 + 1] = v.y;
      Bs[r][c4 * 4 + 2] = v.z; Bs[r][c4 * 4 + 3] = v.w;
    }
    __syncthreads();
#pragma unroll 8
    for (int k2 = 0; k2 < 64; ++k2) {
      float a[4], b4[4];
#pragma unroll
      for (int ii = 0; ii < 4; ++ii) a[ii] = As[tm * 4 + ii][k2];
#pragma unroll
      for (int jj = 0; jj < 4; ++jj) b4[jj] = Bs[k2][tn * 4 + jj];
#pragma unroll
      for (int ii = 0; ii < 4; ++ii)
#pragma unroll
        for (int jj = 0; jj < 4; ++jj)
          acc[ii][jj] = fmaf(a[ii], b4[jj], acc[ii][jj]);
    }
    __syncthreads();
  }
#pragma unroll
  for (int ii = 0; ii < 4; ++ii) {
    int row = row0 + tm * 4 + ii;
    int bb = row >> 10, tt = row & 1023;
#pragma unroll
    for (int jj = 0; jj < 4; ++jj) {
      int col = col0 + tn * 4 + jj;
      int hh = col >> 7, ee = col & 127;
      out[(((size_t)bb * H_ + hh) * T_ + tt) * E_ + ee] = acc[ii][jj] * scale;
    }
  }
}

// ---------------- kernel 2: per-token hypernet + points + weights ----------------
__global__ __launch_bounds__(64)
void token_kernel(const float* __restrict__ x,
                  const float* __restrict__ Wp1, const float* __restrict__ bp1,
                  const float* __restrict__ Wp2, const float* __restrict__ bp2,
                  const float* __restrict__ mv,
                  int* __restrict__ codes_out, float* __restrict__ w_out) {
  int blk = blockIdx.x;            // b*T + t
  int t = blk & 1023;
  int lane = threadIdx.x;

  __shared__ float xs[E_];
  __shared__ float hs[HID_];
  __shared__ float ps[24];
  __shared__ float m0s[KMIX], m1s[KMIX], sgs[KMIX];
  __shared__ int   fl0s[KMIX], fl1s[KMIX], b0s[KMIX], b1s[KMIX];
  __shared__ int   cs[NPTS_];
  __shared__ float mvs[KMIX];

  xs[lane]      = x[(size_t)blk * E_ + lane];
  xs[lane + 64] = x[(size_t)blk * E_ + lane + 64];
  if (lane < KMIX) mvs[lane] = mv[lane];
  __syncthreads();

  // h = relu(x @ Wp1 + bp1)  -- lane j computes h[j]
  {
    float acc = bp1[lane];
    for (int c = 0; c < E_; ++c) acc = fmaf(xs[c], Wp1[c * HID_ + lane], acc);
    hs[lane] = fmaxf(acc, 0.f);
  }
  __syncthreads();

  if (lane < 24) {
    float p = bp2[lane];
    for (int jj = 0; jj < HID_; ++jj) p = fmaf(hs[jj], Wp2[jj * 24 + lane], p);
    ps[lane] = p;
  }
  __syncthreads();

  if (lane < KMIX) {
    float m0 = ps[2 * lane] + (float)t;
    float m1 = ps[2 * lane + 1] + (float)t;
    if (m1 > m0) { float tmp = m0; m0 = m1; m1 = tmp; }   // _flip
    m0 = fminf(fmaxf(m0, 0.f), (float)(T_ - 1));
    m1 = fminf(fmaxf(m1, 0.f), (float)(T_ - 1));
    float sr = ps[16 + lane] + 2.0f;                       // SIGMA_BOOST
    float sig = fmaxf(sr, 0.f) + log1pf(expf(-fabsf(sr))) + 0.01f;  // softplus + MIN_SIGMA
    m0s[lane] = m0; m1s[lane] = m1; sgs[lane] = sig;
    int f0 = (int)floorf(m0), f1 = (int)floorf(m1);
    fl0s[lane] = f0; fl1s[lane] = f1;
    b0s[lane] = min(max(f0 - 1, 0), T_ - 2);
    b1s[lane] = min(max(f1 - 1, 0), T_ - 2);
  }
  __syncthreads();

  // one point per lane: k = lane>>3, slot = lane&7: [c0..c3, g0,g1, l0,l1]
  int k = lane >> 3, s = lane & 7;
  int i, j;
  if (s < 4) {
    i = min(fl0s[k] + (s >> 1), T_ - 1);
    j = min(fl1s[k] + (s & 1), T_ - 1);
  } else if (s < 6) {
    uint32_t k0, k1;
    derive_lower_key(0, k0, k1);
    uint32_t base = ((((uint32_t)blk) * 8u + (uint32_t)k) * 2u + (uint32_t)(s - 4)) * 2u;
    i = (int)(rand_bits32(k0, k1, base + 0u) & 1023u);
    j = (int)(rand_bits32(k0, k1, base + 1u) & 1023u);
  } else {
    uint32_t k0, k1;
    derive_lower_key(1, k0, k1);
    uint32_t base = ((((uint32_t)blk) * 8u + (uint32_t)k) * 2u + (uint32_t)(s - 6)) * 2u;
    i = b0s[k] + (int)(rand_bits32(k0, k1, base + 0u) & 1u);
    j = b1s[k] + (int)(rand_bits32(k0, k1, base + 1u) & 1u);
  }
  if (j > i) { int tmp = i; i = j; j = tmp; }              // _flip on indices
  int code = (i << 10) | j;
  cs[lane] = code;
  __syncthreads();

  bool dup = false;
  for (int m = 0; m < lane; ++m) dup = dup || (cs[m] == code);

  float d[KMIX];
  float fi = (float)i, fj = (float)j;
#pragma unroll
  for (int kk = 0; kk < KMIX; ++kk) {
    float r0 = (fi - m0s[kk]) / sgs[kk];
    float r1 = (fj - m1s[kk]) / sgs[kk];
    d[kk] = dup ? 0.f : expf(-0.5f * (r0 * r0 + r1 * r1));
  }
  float w = 0.f;
#pragma unroll
  for (int kk = 0; kk < KMIX; ++kk) {
    float ssum = d[kk];
#pragma unroll
    for (int off = 32; off > 0; off >>= 1) ssum += __shfl_xor(ssum, off, 64);
    w += mvs[kk] * (d[kk] / ssum);
  }
  codes_out[(size_t)blk * NPTS_ + lane] = code;
  w_out[(size_t)blk * NPTS_ + lane] = w;
}

// ---------------- kernel 3: scatter attention (one wave per contribution) ----------------
__global__ __launch_bounds__(256)
void scatter_kernel(const int* __restrict__ codes, const float* __restrict__ wv,
                    const float* __restrict__ Qw, const float* __restrict__ Kw,
                    const float* __restrict__ Vw, float* __restrict__ att) {
  int wid = (int)((blockIdx.x * 256u + threadIdx.x) >> 6);   // contribution id
  int lane = threadIdx.x & 63;
  int code = codes[wid];
  float w = wv[wid];
  if (w == 0.f) return;                                       // dups contribute nothing
  int b = wid >> 16;                                          // T*NPTS = 65536
  int i = code >> 10, j = code & 1023;
  const float* Qb = Qw + (size_t)b * H_ * T_ * E_;
  const float* Kb = Kw + (size_t)b * H_ * T_ * E_;
  const float* Vb = Vw + (size_t)b * H_ * T_ * E_;
  float* Ab = att + (size_t)b * H_ * T_ * E_;
#pragma unroll
  for (int h = 0; h < H_; ++h) {
    const float* qrow = Qb + ((size_t)h * T_ + i) * E_;
    const float* krow = Kb + ((size_t)h * T_ + j) * E_;
    const float* vrow = Vb + ((size_t)h * T_ + j) * E_;
    float2 q = *(const float2*)(qrow + lane * 2);
    float2 kk = *(const float2*)(krow + lane * 2);
    float p = q.x * kk.x + q.y * kk.y;
#pragma unroll
    for (int off = 32; off > 0; off >>= 1) p += __shfl_xor(p, off, 64);
    float val = p * w;
    float2 v = *(const float2*)(vrow + lane * 2);
    float* arow = Ab + ((size_t)h * T_ + i) * E_ + lane * 2;
    unsafeAtomicAdd(arow + 0, val * v.x);
    unsafeAtomicAdd(arow + 1, val * v.y);
  }
}

// ---------------- kernel 4: output projection  out = att' @ Wu + bu ----------------
__global__ __launch_bounds__(256)
void outproj_kernel(const float* __restrict__ att, const float* __restrict__ Wu,
                    const float* __restrict__ bu, float* __restrict__ out) {
  __shared__ float As[64][65];
  __shared__ float Bs[64][68];
  int tid = threadIdx.x;
  int tm = tid >> 4, tn = tid & 15;
  int row0 = blockIdx.x * 64;   // rows = b*T + t
  int col0 = blockIdx.y * 64;   // 0 or 64
  float acc[4][4] = {};
  for (int kk = 0; kk < 1024; kk += 64) {
    int hh = kk >> 7, e0 = kk & 127;
#pragma unroll
    for (int l = 0; l < 4; ++l) {
      int idx = tid + l * 256;
      int r = idx >> 4, c4 = idx & 15;
      int row = row0 + r;
      int bb = row >> 10, tt = row & 1023;
      float4 v = *(const float4*)(att + (((size_t)bb * H_ + hh) * T_ + tt) * E_ + e0 + c4 * 4);
      As[r][c4 * 4 + 0] = v.x; As[r][c4 * 4 + 1] = v.y;
      As[r][c4 * 4 + 2] = v.z; As[r][c4 * 4 + 3] = v.w;
    }
#pragma unroll
    for (int l = 0; l < 4; ++l) {
      int idx = tid + l * 256;
      int r = idx >> 4, c4 = idx & 15;
      float4 v = *(const float4*)(Wu + (size_t)(kk + r) * 128 + col0 + c4 * 4);
      Bs[r][c4 * 4 + 0] = v.x; Bs[r][c4 * 4 + 1] = v.y;
      Bs[r][c4 * 4 + 2] = v.z; Bs[r][c4 * 4 + 3] = v.w;
    }
    __syncthreads();
#pragma unroll 8
    for (int k2 = 0; k2 < 64; ++k2) {
      float a[4], b4[4];
#pragma unroll
      for (int ii = 0; ii < 4; ++ii) a[ii] = As[tm * 4 + ii][k2];
#pragma unroll
      for (int jj = 0; jj < 4; ++jj) b4[jj] = Bs[k2][tn * 4 + jj];
#pragma unroll
      for (int ii = 0; ii < 4; ++ii)
#pragma unroll
        for (int jj = 0; jj < 4; ++jj)
          acc[ii][jj] = fmaf(a[ii], b4[jj], acc[ii][jj]);
    }
    __syncthreads();
  }
#pragma unroll
  for (int ii = 0; ii < 4; ++ii) {
    int row = row0 + tm * 4 + ii;
#pragma unroll
    for (int jj = 0; jj < 4; ++jj) {
      int col = col0 + tn * 4 + jj;
      out[(size_t)row * 128 + col] = acc[ii][jj] + bu[col];
    }
  }
}

extern "C" void kernel_launch(void* const* d_in, const int* in_sizes, int n_in,
                              void* d_out, int out_size, void* d_ws, size_t ws_size,
                              hipStream_t stream) {
  const float* x   = (const float*)d_in[0];
  const float* Wq  = (const float*)d_in[1];
  const float* Wk  = (const float*)d_in[2];
  const float* Wv  = (const float*)d_in[3];
  const float* Wu  = (const float*)d_in[4];
  const float* bu  = (const float*)d_in[5];
  const float* Wp1 = (const float*)d_in[6];
  const float* bp1 = (const float*)d_in[7];
  const float* Wp2 = (const float*)d_in[8];
  const float* bp2 = (const float*)d_in[9];
  const float* mv  = (const float*)d_in[10];
  float* out = (float*)d_out;

  const size_t NF = (size_t)B_ * H_ * T_ * E_;   // 2097152 floats per tensor
  float* Qw   = (float*)d_ws;
  float* Kw   = Qw + NF;
  float* Vw   = Kw + NF;
  float* att  = Vw + NF;
  int*   codes = (int*)(att + NF);
  float* wv_   = (float*)(codes + NCONTRIB);

  const float scale = 0.29730177875068026f;      // 128^-0.25

  proj_kernel<<<dim3(32, 16), 256, 0, stream>>>(x, Wq, Qw, scale);
  proj_kernel<<<dim3(32, 16), 256, 0, stream>>>(x, Wk, Kw, scale);
  proj_kernel<<<dim3(32, 16), 256, 0, stream>>>(x, Wv, Vw, 1.0f);
  token_kernel<<<B_ * T_, 64, 0, stream>>>(x, Wp1, bp1, Wp2, bp2, mv, codes, wv_);
  hipMemsetAsync(att, 0, NF * sizeof(float), stream);
  scatter_kernel<<<NCONTRIB / 4, 256, 0, stream>>>(codes, wv_, Qw, Kw, Vw, att);
  outproj_kernel<<<dim3(32, 2), 256, 0, stream>>>(att, Wu, bu, out);
}

// Round 5
// 197.492 us; speedup vs baseline: 1.9217x; 1.9217x over previous
//
#include <hip/hip_runtime.h>
#include <stdint.h>

#define B_ 2
#define T_ 1024
#define E_ 128
#define H_ 8
#define KMIX 8
#define NPTS_ 64
#define HID_ 64
#define NCONTRIB (B_ * T_ * NPTS_)   // 131072
#define NROWS (B_ * T_)              // 2048 buckets

#define PARTITIONABLE 1

// ---------------- threefry2x32 (JAX/Random123) ----------------
__device__ __forceinline__ void tf2x32(uint32_t k0, uint32_t k1,
                                       uint32_t x0, uint32_t x1,
                                       uint32_t& o0, uint32_t& o1) {
  uint32_t ks2 = k0 ^ k1 ^ 0x1BD11BDAu;
  x0 += k0; x1 += k1;
#define RND(r) { x0 += x1; x1 = (x1 << (r)) | (x1 >> (32 - (r))); x1 ^= x0; }
  RND(13) RND(15) RND(26) RND(6)
  x0 += k1;  x1 += ks2 + 1u;
  RND(17) RND(29) RND(16) RND(24)
  x0 += ks2; x1 += k0 + 2u;
  RND(13) RND(15) RND(26) RND(6)
  x0 += k0;  x1 += k1 + 3u;
  RND(17) RND(29) RND(16) RND(24)
  x0 += k1;  x1 += ks2 + 4u;
  RND(13) RND(15) RND(26) RND(6)
  x0 += ks2; x1 += k0 + 5u;
#undef RND
  o0 = x0; o1 = x1;
}

#if PARTITIONABLE
__device__ __forceinline__ void derive_lower_key(int which, uint32_t& k0, uint32_t& k1) {
  uint32_t a0, a1;
  tf2x32(0u, 1u, 0u, (uint32_t)which, a0, a1);      // split(key(1))[which]
  tf2x32(a0, a1, 0u, 1u, k0, k1);                   // split(that)[1] = lower key
}
__device__ __forceinline__ uint32_t rand_bits32(uint32_t k0, uint32_t k1, uint32_t f) {
  uint32_t o0, o1;
  tf2x32(k0, k1, 0u, f, o0, o1);
  return o0 ^ o1;                                   // partitionable 32-bit draw
}
#else
__device__ __forceinline__ void split2_legacy(uint32_t k0, uint32_t k1,
                                              uint32_t& a0, uint32_t& a1,
                                              uint32_t& b0, uint32_t& b1) {
  uint32_t y00, y10, y01, y11;
  tf2x32(k0, k1, 0u, 2u, y00, y10);
  tf2x32(k0, k1, 1u, 3u, y01, y11);
  a0 = y00; a1 = y01; b0 = y10; b1 = y11;
}
__device__ __forceinline__ void derive_lower_key(int which, uint32_t& k0, uint32_t& k1) {
  uint32_t g0, g1, n0, n1;
  split2_legacy(0u, 1u, g0, g1, n0, n1);
  uint32_t s0 = which ? n0 : g0, s1 = which ? n1 : g1;
  uint32_t j0, j1;
  split2_legacy(s0, s1, j0, j1, k0, k1);
  (void)j0; (void)j1;
}
__device__ __forceinline__ uint32_t rand_bits32(uint32_t k0, uint32_t k1, uint32_t f) {
  uint32_t o0, o1;
  if (f < 32768u) { tf2x32(k0, k1, f, f + 32768u, o0, o1); return o0; }
  tf2x32(k0, k1, f - 32768u, f, o0, o1); return o1;
}
#endif

// ---------------- kernel 1: fused Q/K/V projection  C = x(2048x128) @ W(128x1024) ----------------
// blockIdx.z selects {Wq,Wk,Wv}; stores permuted to [b][h][t][e], scaled.
__global__ __launch_bounds__(256)
void proj3_kernel(const float* __restrict__ A,
                  const float* __restrict__ Wq, const float* __restrict__ Wk,
                  const float* __restrict__ Wv,
                  float* __restrict__ outbase, float scale) {
  const float* W = (blockIdx.z == 0) ? Wq : (blockIdx.z == 1) ? Wk : Wv;
  float sc = (blockIdx.z == 2) ? 1.0f : scale;
  float* out = outbase + (size_t)blockIdx.z * (size_t)B_ * H_ * T_ * E_;

  __shared__ float As[64][65];
  __shared__ float Bs[64][68];
  int tid = threadIdx.x;
  int tm = tid >> 4, tn = tid & 15;
  int row0 = blockIdx.x * 64;
  int col0 = blockIdx.y * 64;
  float acc[4][4] = {};
  for (int kk = 0; kk < 128; kk += 64) {
#pragma unroll
    for (int l = 0; l < 4; ++l) {
      int idx = tid + l * 256;
      int r = idx >> 4, c4 = idx & 15;
      float4 v = *(const float4*)(A + (size_t)(row0 + r) * 128 + kk + c4 * 4);
      As[r][c4 * 4 + 0] = v.x; As[r][c4 * 4 + 1] = v.y;
      As[r][c4 * 4 + 2] = v.z; As[r][c4 * 4 + 3] = v.w;
    }
#pragma unroll
    for (int l = 0; l < 4; ++l) {
      int idx = tid + l * 256;
      int r = idx >> 4, c4 = idx & 15;
      float4 v = *(const float4*)(W + (size_t)(kk + r) * 1024 + col0 + c4 * 4);
      Bs[r][c4 * 4 + 0] = v.x; Bs[r][c4 * 4 + 1] = v.y;
      Bs[r][c4 * 4 + 2] = v.z; Bs[r][c4 * 4 + 3] = v.w;
    }
    __syncthreads();
#pragma unroll 8
    for (int k2 = 0; k2 < 64; ++k2) {
      float a[4], b4[4];
#pragma unroll
      for (int ii = 0; ii < 4; ++ii) a[ii] = As[tm * 4 + ii][k2];
#pragma unroll
      for (int jj = 0; jj < 4; ++jj) b4[jj] = Bs[k2][tn * 4 + jj];
#pragma unroll
      for (int ii = 0; ii < 4; ++ii)
#pragma unroll
        for (int jj = 0; jj < 4; ++jj)
          acc[ii][jj] = fmaf(a[ii], b4[jj], acc[ii][jj]);
    }
    __syncthreads();
  }
#pragma unroll
  for (int ii = 0; ii < 4; ++ii) {
    int row = row0 + tm * 4 + ii;
    int bb = row >> 10, tt = row & 1023;
#pragma unroll
    for (int jj = 0; jj < 4; ++jj) {
      int col = col0 + tn * 4 + jj;
      int hh = col >> 7, ee = col & 127;
      out[(((size_t)bb * H_ + hh) * T_ + tt) * E_ + ee] = acc[ii][jj] * sc;
    }
  }
}

// ---------------- kernel 2: per-token hypernet + points + weights + row histogram ----------------
__global__ __launch_bounds__(64)
void token_kernel(const float* __restrict__ x,
                  const float* __restrict__ Wp1, const float* __restrict__ bp1,
                  const float* __restrict__ Wp2, const float* __restrict__ bp2,
                  const float* __restrict__ mv,
                  int* __restrict__ codes_out, float* __restrict__ w_out,
                  int* __restrict__ counts) {
  int blk = blockIdx.x;            // b*T + t
  int t = blk & 1023;
  int lane = threadIdx.x;

  __shared__ float xs[E_];
  __shared__ float hs[HID_];
  __shared__ float ps[24];
  __shared__ float m0s[KMIX], m1s[KMIX], sgs[KMIX];
  __shared__ int   fl0s[KMIX], fl1s[KMIX], b0s[KMIX], b1s[KMIX];
  __shared__ int   cs[NPTS_];
  __shared__ float mvs[KMIX];

  xs[lane]      = x[(size_t)blk * E_ + lane];
  xs[lane + 64] = x[(size_t)blk * E_ + lane + 64];
  if (lane < KMIX) mvs[lane] = mv[lane];
  __syncthreads();

  {
    float acc = bp1[lane];
    for (int c = 0; c < E_; ++c) acc = fmaf(xs[c], Wp1[c * HID_ + lane], acc);
    hs[lane] = fmaxf(acc, 0.f);
  }
  __syncthreads();

  if (lane < 24) {
    float p = bp2[lane];
    for (int jj = 0; jj < HID_; ++jj) p = fmaf(hs[jj], Wp2[jj * 24 + lane], p);
    ps[lane] = p;
  }
  __syncthreads();

  if (lane < KMIX) {
    float m0 = ps[2 * lane] + (float)t;
    float m1 = ps[2 * lane + 1] + (float)t;
    if (m1 > m0) { float tmp = m0; m0 = m1; m1 = tmp; }   // _flip
    m0 = fminf(fmaxf(m0, 0.f), (float)(T_ - 1));
    m1 = fminf(fmaxf(m1, 0.f), (float)(T_ - 1));
    float sr = ps[16 + lane] + 2.0f;                       // SIGMA_BOOST
    float sig = fmaxf(sr, 0.f) + log1pf(expf(-fabsf(sr))) + 0.01f;  // softplus + MIN_SIGMA
    m0s[lane] = m0; m1s[lane] = m1; sgs[lane] = sig;
    int f0 = (int)floorf(m0), f1 = (int)floorf(m1);
    fl0s[lane] = f0; fl1s[lane] = f1;
    b0s[lane] = min(max(f0 - 1, 0), T_ - 2);
    b1s[lane] = min(max(f1 - 1, 0), T_ - 2);
  }
  __syncthreads();

  // one point per lane: k = lane>>3, slot = lane&7: [c0..c3, g0,g1, l0,l1]
  int k = lane >> 3, s = lane & 7;
  int i, j;
  if (s < 4) {
    i = min(fl0s[k] + (s >> 1), T_ - 1);
    j = min(fl1s[k] + (s & 1), T_ - 1);
  } else if (s < 6) {
    uint32_t k0, k1;
    derive_lower_key(0, k0, k1);
    uint32_t base = ((((uint32_t)blk) * 8u + (uint32_t)k) * 2u + (uint32_t)(s - 4)) * 2u;
    i = (int)(rand_bits32(k0, k1, base + 0u) & 1023u);
    j = (int)(rand_bits32(k0, k1, base + 1u) & 1023u);
  } else {
    uint32_t k0, k1;
    derive_lower_key(1, k0, k1);
    uint32_t base = ((((uint32_t)blk) * 8u + (uint32_t)k) * 2u + (uint32_t)(s - 6)) * 2u;
    i = b0s[k] + (int)(rand_bits32(k0, k1, base + 0u) & 1u);
    j = b1s[k] + (int)(rand_bits32(k0, k1, base + 1u) & 1u);
  }
  if (j > i) { int tmp = i; i = j; j = tmp; }              // _flip on indices
  int code = (i << 10) | j;
  cs[lane] = code;
  __syncthreads();

  bool dup = false;
  for (int m = 0; m < lane; ++m) dup = dup || (cs[m] == code);

  float d[KMIX];
  float fi = (float)i, fj = (float)j;
#pragma unroll
  for (int kk = 0; kk < KMIX; ++kk) {
    float r0 = (fi - m0s[kk]) / sgs[kk];
    float r1 = (fj - m1s[kk]) / sgs[kk];
    d[kk] = dup ? 0.f : expf(-0.5f * (r0 * r0 + r1 * r1));
  }
  float w = 0.f;
#pragma unroll
  for (int kk = 0; kk < KMIX; ++kk) {
    float ssum = d[kk];
#pragma unroll
    for (int off = 32; off > 0; off >>= 1) ssum += __shfl_xor(ssum, off, 64);
    w += mvs[kk] * (d[kk] / ssum);
  }
  codes_out[(size_t)blk * NPTS_ + lane] = code;
  w_out[(size_t)blk * NPTS_ + lane] = w;
  if (w != 0.f) {
    int key = ((blk >> 10) << 10) | i;    // b*1024 + i
    atomicAdd(&counts[key], 1);
  }
}

// ---------------- kernel 3: exclusive scan over 2048 buckets (single block) ----------------
__global__ __launch_bounds__(1024)
void scan_kernel(const int* __restrict__ counts, int* __restrict__ offsets,
                 int* __restrict__ cursor) {
  __shared__ int a[NROWS];
  __shared__ int bbuf[NROWS];
  int tid = threadIdx.x;
  a[tid] = counts[tid]; a[tid + 1024] = counts[tid + 1024];
  __syncthreads();
  int* src = a; int* dst = bbuf;
  for (int off = 1; off < NROWS; off <<= 1) {
    for (int idx = tid; idx < NROWS; idx += 1024) {
      int v = src[idx];
      if (idx >= off) v += src[idx - off];
      dst[idx] = v;
    }
    __syncthreads();
    int* tswap = src; src = dst; dst = tswap;
  }
  for (int idx = tid; idx < NROWS; idx += 1024) {
    int excl = src[idx] - counts[idx];
    offsets[idx] = excl;
    cursor[idx] = excl;
  }
}

// ---------------- kernel 4: reorder contributions into row buckets ----------------
__global__ __launch_bounds__(256)
void reorder_kernel(const int* __restrict__ codes, const float* __restrict__ wv,
                    int* __restrict__ cursor, int2* __restrict__ entries) {
  int c = blockIdx.x * 256 + threadIdx.x;
  float w = wv[c];
  if (w == 0.f) return;
  int code = codes[c];
  int b = c >> 16;                       // T*NPTS = 65536 per batch
  int key = (b << 10) | (code >> 10);
  int pos = atomicAdd(cursor + key, 1);
  entries[pos] = make_int2(code & 1023, __float_as_int(w));
}

// ---------------- kernel 5: gather attention (block per row, wave per head) ----------------
__global__ __launch_bounds__(512)
void gather_kernel(const int2* __restrict__ entries, const int* __restrict__ offsets,
                   const int* __restrict__ counts,
                   const float* __restrict__ Qw, const float* __restrict__ Kw,
                   const float* __restrict__ Vw, float* __restrict__ att) {
  int key = blockIdx.x;                  // b*1024 + i
  int b = key >> 10, i = key & 1023;
  int h = threadIdx.x >> 6, lane = threadIdx.x & 63;
  int start = offsets[key], n = counts[key];

  const float* Qrow = Qw + (((size_t)b * H_ + h) * T_ + i) * E_;
  const float* Kh = Kw + ((size_t)b * H_ + h) * (size_t)T_ * E_;
  const float* Vh = Vw + ((size_t)b * H_ + h) * (size_t)T_ * E_;
  float2 q = *(const float2*)(Qrow + lane * 2);
  float2 acc = {0.f, 0.f};

  for (int e = 0; e < n; ++e) {
    int2 ent = entries[start + e];
    int j = ent.x;
    float wgt = __int_as_float(ent.y);
    float2 kk = *(const float2*)(Kh + (size_t)j * E_ + lane * 2);
    float p = q.x * kk.x + q.y * kk.y;
#pragma unroll
    for (int off = 32; off > 0; off >>= 1) p += __shfl_xor(p, off, 64);
    float val = p * wgt;
    float2 v = *(const float2*)(Vh + (size_t)j * E_ + lane * 2);
    acc.x = fmaf(val, v.x, acc.x);
    acc.y = fmaf(val, v.y, acc.y);
  }
  float* arow = att + (((size_t)b * H_ + h) * T_ + i) * E_ + lane * 2;
  *(float2*)arow = acc;   // writes zeros for empty rows -> no memset needed
}

// ---------------- kernel 6: output projection  out = att' @ Wu + bu ----------------
__global__ __launch_bounds__(256)
void outproj_kernel(const float* __restrict__ att, const float* __restrict__ Wu,
                    const float* __restrict__ bu, float* __restrict__ out) {
  __shared__ float As[64][65];
  __shared__ float Bs[64][68];
  int tid = threadIdx.x;
  int tm = tid >> 4, tn = tid & 15;
  int row0 = blockIdx.x * 64;   // rows = b*T + t
  int col0 = blockIdx.y * 64;   // 0 or 64
  float acc[4][4] = {};
  for (int kk = 0; kk < 1024; kk += 64) {
    int hh = kk >> 7, e0 = kk & 127;
#pragma unroll
    for (int l = 0; l < 4; ++l) {
      int idx = tid + l * 256;
      int r = idx >> 4, c4 = idx & 15;
      int row = row0 + r;
      int bb = row >> 10, tt = row & 1023;
      float4 v = *(const float4*)(att + (((size_t)bb * H_ + hh) * T_ + tt) * E_ + e0 + c4 * 4);
      As[r][c4 * 4 + 0] = v.x; As[r][c4 * 4 + 1] = v.y;
      As[r][c4 * 4 + 2] = v.z; As[r][c4 * 4 + 3] = v.w;
    }
#pragma unroll
    for (int l = 0; l < 4; ++l) {
      int idx = tid + l * 256;
      int r = idx >> 4, c4 = idx & 15;
      float4 v = *(const float4*)(Wu + (size_t)(kk + r) * 128 + col0 + c4 * 4);
      Bs[r][c4 * 4 + 0] = v.x; Bs[r][c4 * 4 + 1] = v.y;
      Bs[r][c4 * 4 + 2] = v.z; Bs[r][c4 * 4 + 3] = v.w;
    }
    __syncthreads();
#pragma unroll 8
    for (int k2 = 0; k2 < 64; ++k2) {
      float a[4], b4[4];
#pragma unroll
      for (int ii = 0; ii < 4; ++ii) a[ii] = As[tm * 4 + ii][k2];
#pragma unroll
      for (int jj = 0; jj < 4; ++jj) b4[jj] = Bs[k2][tn * 4 + jj];
#pragma unroll
      for (int ii = 0; ii < 4; ++ii)
#pragma unroll
        for (int jj = 0; jj < 4; ++jj)
          acc[ii][jj] = fmaf(a[ii], b4[jj], acc[ii][jj]);
    }
    __syncthreads();
  }
#pragma unroll
  for (int ii = 0; ii < 4; ++ii) {
    int row = row0 + tm * 4 + ii;
#pragma unroll
    for (int jj = 0; jj < 4; ++jj) {
      int col = col0 + tn * 4 + jj;
      out[(size_t)row * 128 + col] = acc[ii][jj] + bu[col];
    }
  }
}

extern "C" void kernel_launch(void* const* d_in, const int* in_sizes, int n_in,
                              void* d_out, int out_size, void* d_ws, size_t ws_size,
                              hipStream_t stream) {
  const float* x   = (const float*)d_in[0];
  const float* Wq  = (const float*)d_in[1];
  const float* Wk  = (const float*)d_in[2];
  const float* Wv  = (const float*)d_in[3];
  const float* Wu  = (const float*)d_in[4];
  const float* bu  = (const float*)d_in[5];
  const float* Wp1 = (const float*)d_in[6];
  const float* bp1 = (const float*)d_in[7];
  const float* Wp2 = (const float*)d_in[8];
  const float* bp2 = (const float*)d_in[9];
  const float* mv  = (const float*)d_in[10];
  float* out = (float*)d_out;

  const size_t NF = (size_t)B_ * H_ * T_ * E_;   // 2097152 floats per tensor
  float* Qw      = (float*)d_ws;                 // Q,K,V contiguous (proj3 indexes by z)
  float* Kw      = Qw + NF;
  float* Vw      = Kw + NF;
  float* att     = Vw + NF;
  int*   codes   = (int*)(att + NF);
  float* wv_     = (float*)(codes + NCONTRIB);
  int*   counts  = (int*)(wv_ + NCONTRIB);
  int*   offsets = counts + NROWS;
  int*   cursor  = offsets + NROWS;
  int2*  entries = (int2*)(cursor + NROWS);      // <= NCONTRIB entries

  const float scale = 0.29730177875068026f;      // 128^-0.25

  hipMemsetAsync(counts, 0, NROWS * sizeof(int), stream);
  proj3_kernel<<<dim3(32, 16, 3), 256, 0, stream>>>(x, Wq, Wk, Wv, Qw, scale);
  token_kernel<<<NROWS, 64, 0, stream>>>(x, Wp1, bp1, Wp2, bp2, mv, codes, wv_, counts);
  scan_kernel<<<1, 1024, 0, stream>>>(counts, offsets, cursor);
  reorder_kernel<<<NCONTRIB / 256, 256, 0, stream>>>(codes, wv_, cursor, entries);
  gather_kernel<<<NROWS, 512, 0, stream>>>(entries, offsets, counts, Qw, Kw, Vw, att);
  outproj_kernel<<<dim3(32, 2), 256, 0, stream>>>(att, Wu, bu, out);
}

// Round 7
// 165.081 us; speedup vs baseline: 2.2990x; 1.1963x over previous
//
#include <hip/hip_runtime.h>
#include <stdint.h>

#define B_ 2
#define T_ 1024
#define E_ 128
#define H_ 8
#define KMIX 8
#define NPTS_ 64
#define HID_ 64
#define NCONTRIB (B_ * T_ * NPTS_)   // 131072
#define NROWS (B_ * T_)              // 2048 buckets

#define PARTITIONABLE 1

// ---------------- threefry2x32 (JAX/Random123) ----------------
__device__ __forceinline__ void tf2x32(uint32_t k0, uint32_t k1,
                                       uint32_t x0, uint32_t x1,
                                       uint32_t& o0, uint32_t& o1) {
  uint32_t ks2 = k0 ^ k1 ^ 0x1BD11BDAu;
  x0 += k0; x1 += k1;
#define RND(r) { x0 += x1; x1 = (x1 << (r)) | (x1 >> (32 - (r))); x1 ^= x0; }
  RND(13) RND(15) RND(26) RND(6)
  x0 += k1;  x1 += ks2 + 1u;
  RND(17) RND(29) RND(16) RND(24)
  x0 += ks2; x1 += k0 + 2u;
  RND(13) RND(15) RND(26) RND(6)
  x0 += k0;  x1 += k1 + 3u;
  RND(17) RND(29) RND(16) RND(24)
  x0 += k1;  x1 += ks2 + 4u;
  RND(13) RND(15) RND(26) RND(6)
  x0 += ks2; x1 += k0 + 5u;
#undef RND
  o0 = x0; o1 = x1;
}

#if PARTITIONABLE
__device__ __forceinline__ void derive_lower_key(int which, uint32_t& k0, uint32_t& k1) {
  uint32_t a0, a1;
  tf2x32(0u, 1u, 0u, (uint32_t)which, a0, a1);      // split(key(1))[which]
  tf2x32(a0, a1, 0u, 1u, k0, k1);                   // split(that)[1] = lower key
}
__device__ __forceinline__ uint32_t rand_bits32(uint32_t k0, uint32_t k1, uint32_t f) {
  uint32_t o0, o1;
  tf2x32(k0, k1, 0u, f, o0, o1);
  return o0 ^ o1;                                   // partitionable 32-bit draw
}
#else
__device__ __forceinline__ void split2_legacy(uint32_t k0, uint32_t k1,
                                              uint32_t& a0, uint32_t& a1,
                                              uint32_t& b0, uint32_t& b1) {
  uint32_t y00, y10, y01, y11;
  tf2x32(k0, k1, 0u, 2u, y00, y10);
  tf2x32(k0, k1, 1u, 3u, y01, y11);
  a0 = y00; a1 = y01; b0 = y10; b1 = y11;
}
__device__ __forceinline__ void derive_lower_key(int which, uint32_t& k0, uint32_t& k1) {
  uint32_t g0, g1, n0, n1;
  split2_legacy(0u, 1u, g0, g1, n0, n1);
  uint32_t s0 = which ? n0 : g0, s1 = which ? n1 : g1;
  uint32_t j0, j1;
  split2_legacy(s0, s1, j0, j1, k0, k1);
  (void)j0; (void)j1;
}
__device__ __forceinline__ uint32_t rand_bits32(uint32_t k0, uint32_t k1, uint32_t f) {
  uint32_t o0, o1;
  if (f < 32768u) { tf2x32(k0, k1, f, f + 32768u, o0, o1); return o0; }
  tf2x32(k0, k1, f - 32768u, f, o0, o1); return o1;
}
#endif

// ---------------- kernel 1: fused Q/K/V projection  C = x(2048x128) @ W(128x1024) ----------------
// blockIdx.z selects {Wq,Wk,Wv}; stores permuted to [b][h][t][e], scaled.
__global__ __launch_bounds__(256)
void proj3_kernel(const float* __restrict__ A,
                  const float* __restrict__ Wq, const float* __restrict__ Wk,
                  const float* __restrict__ Wv,
                  float* __restrict__ outbase, float scale) {
  const float* W = (blockIdx.z == 0) ? Wq : (blockIdx.z == 1) ? Wk : Wv;
  float sc = (blockIdx.z == 2) ? 1.0f : scale;
  float* out = outbase + (size_t)blockIdx.z * (size_t)B_ * H_ * T_ * E_;

  __shared__ float As[64][65];
  __shared__ float Bs[64][68];
  int tid = threadIdx.x;
  int tm = tid >> 4, tn = tid & 15;
  int row0 = blockIdx.x * 64;
  int col0 = blockIdx.y * 64;
  float acc[4][4] = {};
  for (int kk = 0; kk < 128; kk += 64) {
#pragma unroll
    for (int l = 0; l < 4; ++l) {
      int idx = tid + l * 256;
      int r = idx >> 4, c4 = idx & 15;
      float4 v = *(const float4*)(A + (size_t)(row0 + r) * 128 + kk + c4 * 4);
      As[r][c4 * 4 + 0] = v.x; As[r][c4 * 4 + 1] = v.y;
      As[r][c4 * 4 + 2] = v.z; As[r][c4 * 4 + 3] = v.w;
    }
#pragma unroll
    for (int l = 0; l < 4; ++l) {
      int idx = tid + l * 256;
      int r = idx >> 4, c4 = idx & 15;
      float4 v = *(const float4*)(W + (size_t)(kk + r) * 1024 + col0 + c4 * 4);
      Bs[r][c4 * 4 + 0] = v.x; Bs[r][c4 * 4 + 1] = v.y;
      Bs[r][c4 * 4 + 2] = v.z; Bs[r][c4 * 4 + 3] = v.w;
    }
    __syncthreads();
#pragma unroll 8
    for (int k2 = 0; k2 < 64; ++k2) {
      float a[4], b4[4];
#pragma unroll
      for (int ii = 0; ii < 4; ++ii) a[ii] = As[tm * 4 + ii][k2];
#pragma unroll
      for (int jj = 0; jj < 4; ++jj) b4[jj] = Bs[k2][tn * 4 + jj];
#pragma unroll
      for (int ii = 0; ii < 4; ++ii)
#pragma unroll
        for (int jj = 0; jj < 4; ++jj)
          acc[ii][jj] = fmaf(a[ii], b4[jj], acc[ii][jj]);
    }
    __syncthreads();
  }
#pragma unroll
  for (int ii = 0; ii < 4; ++ii) {
    int row = row0 + tm * 4 + ii;
    int bb = row >> 10, tt = row & 1023;
#pragma unroll
    for (int jj = 0; jj < 4; ++jj) {
      int col = col0 + tn * 4 + jj;
      int hh = col >> 7, ee = col & 127;
      out[(((size_t)bb * H_ + hh) * T_ + tt) * E_ + ee] = acc[ii][jj] * sc;
    }
  }
}

// ---------------- kernel 2: per-token hypernet + points + weights + row histogram ----------------
__global__ __launch_bounds__(64)
void token_kernel(const float* __restrict__ x,
                  const float* __restrict__ Wp1, const float* __restrict__ bp1,
                  const float* __restrict__ Wp2, const float* __restrict__ bp2,
                  const float* __restrict__ mv,
                  int* __restrict__ codes_out, float* __restrict__ w_out,
                  int* __restrict__ counts) {
  int blk = blockIdx.x;            // b*T + t
  int t = blk & 1023;
  int lane = threadIdx.x;

  __shared__ float xs[E_];
  __shared__ float hs[HID_];
  __shared__ float ps[24];
  __shared__ float m0s[KMIX], m1s[KMIX], sgs[KMIX];
  __shared__ int   fl0s[KMIX], fl1s[KMIX], b0s[KMIX], b1s[KMIX];
  __shared__ int   cs[NPTS_];
  __shared__ float mvs[KMIX];

  xs[lane]      = x[(size_t)blk * E_ + lane];
  xs[lane + 64] = x[(size_t)blk * E_ + lane + 64];
  if (lane < KMIX) mvs[lane] = mv[lane];
  __syncthreads();

  {
    float acc = bp1[lane];
    for (int c = 0; c < E_; ++c) acc = fmaf(xs[c], Wp1[c * HID_ + lane], acc);
    hs[lane] = fmaxf(acc, 0.f);
  }
  __syncthreads();

  if (lane < 24) {
    float p = bp2[lane];
    for (int jj = 0; jj < HID_; ++jj) p = fmaf(hs[jj], Wp2[jj * 24 + lane], p);
    ps[lane] = p;
  }
  __syncthreads();

  if (lane < KMIX) {
    float m0 = ps[2 * lane] + (float)t;
    float m1 = ps[2 * lane + 1] + (float)t;
    if (m1 > m0) { float tmp = m0; m0 = m1; m1 = tmp; }   // _flip
    m0 = fminf(fmaxf(m0, 0.f), (float)(T_ - 1));
    m1 = fminf(fmaxf(m1, 0.f), (float)(T_ - 1));
    float sr = ps[16 + lane] + 2.0f;                       // SIGMA_BOOST
    float sig = fmaxf(sr, 0.f) + log1pf(expf(-fabsf(sr))) + 0.01f;  // softplus + MIN_SIGMA
    m0s[lane] = m0; m1s[lane] = m1; sgs[lane] = sig;
    int f0 = (int)floorf(m0), f1 = (int)floorf(m1);
    fl0s[lane] = f0; fl1s[lane] = f1;
    b0s[lane] = min(max(f0 - 1, 0), T_ - 2);
    b1s[lane] = min(max(f1 - 1, 0), T_ - 2);
  }
  __syncthreads();

  // one point per lane: k = lane>>3, slot = lane&7: [c0..c3, g0,g1, l0,l1]
  int k = lane >> 3, s = lane & 7;
  int i, j;
  if (s < 4) {
    i = min(fl0s[k] + (s >> 1), T_ - 1);
    j = min(fl1s[k] + (s & 1), T_ - 1);
  } else if (s < 6) {
    uint32_t k0, k1;
    derive_lower_key(0, k0, k1);
    uint32_t base = ((((uint32_t)blk) * 8u + (uint32_t)k) * 2u + (uint32_t)(s - 4)) * 2u;
    i = (int)(rand_bits32(k0, k1, base + 0u) & 1023u);
    j = (int)(rand_bits32(k0, k1, base + 1u) & 1023u);
  } else {
    uint32_t k0, k1;
    derive_lower_key(1, k0, k1);
    uint32_t base = ((((uint32_t)blk) * 8u + (uint32_t)k) * 2u + (uint32_t)(s - 6)) * 2u;
    i = b0s[k] + (int)(rand_bits32(k0, k1, base + 0u) & 1u);
    j = b1s[k] + (int)(rand_bits32(k0, k1, base + 1u) & 1u);
  }
  if (j > i) { int tmp = i; i = j; j = tmp; }              // _flip on indices
  int code = (i << 10) | j;
  cs[lane] = code;
  __syncthreads();

  bool dup = false;
  for (int m = 0; m < lane; ++m) dup = dup || (cs[m] == code);

  float d[KMIX];
  float fi = (float)i, fj = (float)j;
#pragma unroll
  for (int kk = 0; kk < KMIX; ++kk) {
    float r0 = (fi - m0s[kk]) / sgs[kk];
    float r1 = (fj - m1s[kk]) / sgs[kk];
    d[kk] = dup ? 0.f : expf(-0.5f * (r0 * r0 + r1 * r1));
  }
  float w = 0.f;
#pragma unroll
  for (int kk = 0; kk < KMIX; ++kk) {
    float ssum = d[kk];
#pragma unroll
    for (int off = 32; off > 0; off >>= 1) ssum += __shfl_xor(ssum, off, 64);
    w += mvs[kk] * (d[kk] / ssum);
  }
  codes_out[(size_t)blk * NPTS_ + lane] = code;
  w_out[(size_t)blk * NPTS_ + lane] = w;
  if (w != 0.f) {
    int key = ((blk >> 10) << 10) | i;    // b*1024 + i
    atomicAdd(&counts[key], 1);
  }
}

// ---------------- kernel 3: exclusive scan over 2048 buckets (single block) ----------------
__global__ __launch_bounds__(1024)
void scan_kernel(const int* __restrict__ counts, int* __restrict__ offsets,
                 int* __restrict__ cursor) {
  __shared__ int a[NROWS];
  __shared__ int bbuf[NROWS];
  int tid = threadIdx.x;
  a[tid] = counts[tid]; a[tid + 1024] = counts[tid + 1024];
  __syncthreads();
  int* src = a; int* dst = bbuf;
  for (int off = 1; off < NROWS; off <<= 1) {
    for (int idx = tid; idx < NROWS; idx += 1024) {
      int v = src[idx];
      if (idx >= off) v += src[idx - off];
      dst[idx] = v;
    }
    __syncthreads();
    int* tswap = src; src = dst; dst = tswap;
  }
  for (int idx = tid; idx < NROWS; idx += 1024) {
    int excl = src[idx] - counts[idx];
    offsets[idx] = excl;
    cursor[idx] = excl;
  }
}

// ---------------- kernel 4: reorder contributions into row buckets ----------------
__global__ __launch_bounds__(256)
void reorder_kernel(const int* __restrict__ codes, const float* __restrict__ wv,
                    int* __restrict__ cursor, int2* __restrict__ entries) {
  int c = blockIdx.x * 256 + threadIdx.x;
  float w = wv[c];
  if (w == 0.f) return;
  int code = codes[c];
  int b = c >> 16;                       // T*NPTS = 65536 per batch
  int key = (b << 10) | (code >> 10);
  int pos = atomicAdd(cursor + key, 1);
  entries[pos] = make_int2(code & 1023, __float_as_int(w));
}

// ---------------- kernel 5: gather attention (block per row, wave per head) ----------------
__global__ __launch_bounds__(512)
void gather_kernel(const int2* __restrict__ entries, const int* __restrict__ offsets,
                   const int* __restrict__ counts,
                   const float* __restrict__ Qw, const float* __restrict__ Kw,
                   const float* __restrict__ Vw, float* __restrict__ att) {
  int key = blockIdx.x;                  // b*1024 + i
  int b = key >> 10, i = key & 1023;
  int h = threadIdx.x >> 6, lane = threadIdx.x & 63;
  int start = offsets[key], n = counts[key];

  const float* Qrow = Qw + (((size_t)b * H_ + h) * T_ + i) * E_;
  const float* Kh = Kw + ((size_t)b * H_ + h) * (size_t)T_ * E_;
  const float* Vh = Vw + ((size_t)b * H_ + h) * (size_t)T_ * E_;
  float2 q = *(const float2*)(Qrow + lane * 2);
  float2 acc = {0.f, 0.f};

  for (int e = 0; e < n; ++e) {
    int2 ent = entries[start + e];
    int j = ent.x;
    float wgt = __int_as_float(ent.y);
    float2 kk = *(const float2*)(Kh + (size_t)j * E_ + lane * 2);
    float p = q.x * kk.x + q.y * kk.y;
#pragma unroll
    for (int off = 32; off > 0; off >>= 1) p += __shfl_xor(p, off, 64);
    float val = p * wgt;
    float2 v = *(const float2*)(Vh + (size_t)j * E_ + lane * 2);
    acc.x = fmaf(val, v.x, acc.x);
    acc.y = fmaf(val, v.y, acc.y);
  }
  float* arow = att + (((size_t)b * H_ + h) * T_ + i) * E_ + lane * 2;
  *(float2*)arow = acc;   // writes zeros for empty rows -> no memset needed
}

// ---------------- kernel 6: split-K output projection ----------------
// partials[z][row][col] = att_head_z_rows @ Wu_head_z_cols ; z = head = K-chunk of 128
__global__ __launch_bounds__(256)
void outproj_split_kernel(const float* __restrict__ att, const float* __restrict__ Wu,
                          float* __restrict__ partials) {
  __shared__ float As[64][65];
  __shared__ float Bs[64][68];
  int tid = threadIdx.x;
  int tm = tid >> 4, tn = tid & 15;
  int row0 = blockIdx.x * 64;   // rows = b*T + t
  int col0 = blockIdx.y * 64;   // 0 or 64
  int hh = blockIdx.z;          // head = K-chunk
  float acc[4][4] = {};
  for (int step = 0; step < 2; ++step) {
    int e0 = step * 64;
#pragma unroll
    for (int l = 0; l < 4; ++l) {
      int idx = tid + l * 256;
      int r = idx >> 4, c4 = idx & 15;
      int row = row0 + r;
      int bb = row >> 10, tt = row & 1023;
      float4 v = *(const float4*)(att + (((size_t)bb * H_ + hh) * T_ + tt) * E_ + e0 + c4 * 4);
      As[r][c4 * 4 + 0] = v.x; As[r][c4 * 4 + 1] = v.y;
      As[r][c4 * 4 + 2] = v.z; As[r][c4 * 4 + 3] = v.w;
    }
#pragma unroll
    for (int l = 0; l < 4; ++l) {
      int idx = tid + l * 256;
      int r = idx >> 4, c4 = idx & 15;
      float4 v = *(const float4*)(Wu + (size_t)(hh * 128 + e0 + r) * 128 + col0 + c4 * 4);
      Bs[r][c4 * 4 + 0] = v.x; Bs[r][c4 * 4 + 1] = v.y;
      Bs[r][c4 * 4 + 2] = v.z; Bs[r][c4 * 4 + 3] = v.w;
    }
    __syncthreads();
#pragma unroll 8
    for (int k2 = 0; k2 < 64; ++k2) {
      float a[4], b4[4];
#pragma unroll
      for (int ii = 0; ii < 4; ++ii) a[ii] = As[tm * 4 + ii][k2];
#pragma unroll
      for (int jj = 0; jj < 4; ++jj) b4[jj] = Bs[k2][tn * 4 + jj];
#pragma unroll
      for (int ii = 0; ii < 4; ++ii)
#pragma unroll
        for (int jj = 0; jj < 4; ++jj)
          acc[ii][jj] = fmaf(a[ii], b4[jj], acc[ii][jj]);
    }
    __syncthreads();
  }
  float* pbase = partials + (size_t)hh * NROWS * 128;
#pragma unroll
  for (int ii = 0; ii < 4; ++ii) {
    int row = row0 + tm * 4 + ii;
#pragma unroll
    for (int jj = 0; jj < 4; ++jj) {
      int col = col0 + tn * 4 + jj;
      pbase[(size_t)row * 128 + col] = acc[ii][jj];
    }
  }
}

// ---------------- kernel 7: reduce 8 partials + bias ----------------
__global__ __launch_bounds__(256)
void reduce_kernel(const float* __restrict__ partials, const float* __restrict__ bu,
                   float* __restrict__ out) {
  int idx = blockIdx.x * 256 + threadIdx.x;    // row*128 + col, 262144 total
  int col = idx & 127;
  float s = bu[col];
#pragma unroll
  for (int z = 0; z < H_; ++z)
    s += partials[(size_t)z * NROWS * 128 + idx];
  out[idx] = s;
}

extern "C" void kernel_launch(void* const* d_in, const int* in_sizes, int n_in,
                              void* d_out, int out_size, void* d_ws, size_t ws_size,
                              hipStream_t stream) {
  const float* x   = (const float*)d_in[0];
  const float* Wq  = (const float*)d_in[1];
  const float* Wk  = (const float*)d_in[2];
  const float* Wv  = (const float*)d_in[3];
  const float* Wu  = (const float*)d_in[4];
  const float* bu  = (const float*)d_in[5];
  const float* Wp1 = (const float*)d_in[6];
  const float* bp1 = (const float*)d_in[7];
  const float* Wp2 = (const float*)d_in[8];
  const float* bp2 = (const float*)d_in[9];
  const float* mv  = (const float*)d_in[10];
  float* out = (float*)d_out;

  const size_t NF = (size_t)B_ * H_ * T_ * E_;   // 2097152 floats per tensor
  float* Qw      = (float*)d_ws;                 // Q,K,V contiguous (proj3 indexes by z)
  float* Kw      = Qw + NF;
  float* Vw      = Kw + NF;
  float* att     = Vw + NF;
  int*   codes   = (int*)(att + NF);
  float* wv_     = (float*)(codes + NCONTRIB);
  int*   counts  = (int*)(wv_ + NCONTRIB);
  int*   offsets = counts + NROWS;
  int*   cursor  = offsets + NROWS;
  int2*  entries = (int2*)(cursor + NROWS);      // <= NCONTRIB entries
  float* partials = (float*)(entries + NCONTRIB); // 8 * 2048 * 128 floats = 8 MB

  const float scale = 0.29730177875068026f;      // 128^-0.25

  hipMemsetAsync(counts, 0, NROWS * sizeof(int), stream);
  proj3_kernel<<<dim3(32, 16, 3), 256, 0, stream>>>(x, Wq, Wk, Wv, Qw, scale);
  token_kernel<<<NROWS, 64, 0, stream>>>(x, Wp1, bp1, Wp2, bp2, mv, codes, wv_, counts);
  scan_kernel<<<1, 1024, 0, stream>>>(counts, offsets, cursor);
  reorder_kernel<<<NCONTRIB / 256, 256, 0, stream>>>(codes, wv_, cursor, entries);
  gather_kernel<<<NROWS, 512, 0, stream>>>(entries, offsets, counts, Qw, Kw, Vw, att);
  outproj_split_kernel<<<dim3(32, 2, 8), 256, 0, stream>>>(att, Wu, partials);
  reduce_kernel<<<NROWS * 128 / 256, 256, 0, stream>>>(partials, bu, out);
}

// Round 11
// 148.888 us; speedup vs baseline: 2.5491x; 1.1088x over previous
//
#include <hip/hip_runtime.h>
#include <stdint.h>

#define B_ 2
#define T_ 1024
#define E_ 128
#define H_ 8
#define KMIX 8
#define NPTS_ 64
#define HID_ 64
#define NROWS (B_ * T_)              // 2048 row buckets
#define CAP 320                      // max entries per row bucket (audit: worst ~250)

// ---------------- threefry2x32 (JAX partitionable stream) ----------------
__device__ __forceinline__ void tf2x32(uint32_t k0, uint32_t k1,
                                       uint32_t x0, uint32_t x1,
                                       uint32_t& o0, uint32_t& o1) {
  uint32_t ks2 = k0 ^ k1 ^ 0x1BD11BDAu;
  x0 += k0; x1 += k1;
#define RND(r) { x0 += x1; x1 = (x1 << (r)) | (x1 >> (32 - (r))); x1 ^= x0; }
  RND(13) RND(15) RND(26) RND(6)
  x0 += k1;  x1 += ks2 + 1u;
  RND(17) RND(29) RND(16) RND(24)
  x0 += ks2; x1 += k0 + 2u;
  RND(13) RND(15) RND(26) RND(6)
  x0 += k0;  x1 += k1 + 3u;
  RND(17) RND(29) RND(16) RND(24)
  x0 += k1;  x1 += ks2 + 4u;
  RND(13) RND(15) RND(26) RND(6)
  x0 += ks2; x1 += k0 + 5u;
#undef RND
  o0 = x0; o1 = x1;
}

// compile-time variant: the two randint lower keys are constants of key(1)
constexpr uint64_t tf_ce(uint32_t k0, uint32_t k1, uint32_t x0, uint32_t x1) {
  uint32_t ks2 = k0 ^ k1 ^ 0x1BD11BDAu;
  x0 += k0; x1 += k1;
#define RND(r) { x0 += x1; x1 = (x1 << (r)) | (x1 >> (32 - (r))); x1 ^= x0; }
  RND(13) RND(15) RND(26) RND(6)
  x0 += k1;  x1 += ks2 + 1u;
  RND(17) RND(29) RND(16) RND(24)
  x0 += ks2; x1 += k0 + 2u;
  RND(13) RND(15) RND(26) RND(6)
  x0 += k0;  x1 += k1 + 3u;
  RND(17) RND(29) RND(16) RND(24)
  x0 += k1;  x1 += ks2 + 4u;
  RND(13) RND(15) RND(26) RND(6)
  x0 += ks2; x1 += k0 + 5u;
#undef RND
  return ((uint64_t)x1 << 32) | x0;
}
constexpr uint64_t lower_key_ce(uint32_t which) {
  uint64_t a = tf_ce(0u, 1u, 0u, which);                       // split(key(1))[which]
  return tf_ce((uint32_t)a, (uint32_t)(a >> 32), 0u, 1u);      // split(that)[1]
}
constexpr uint64_t KG_ = lower_key_ce(0);   // glob randint lower key
constexpr uint64_t KN_ = lower_key_ce(1);   // loc randint lower key

__device__ __forceinline__ uint32_t rand_bits32(uint32_t k0, uint32_t k1, uint32_t f) {
  uint32_t o0, o1;
  tf2x32(k0, k1, 0u, f, o0, o1);
  return o0 ^ o1;                           // partitionable 32-bit draw
}

// ---------------- kernel 1: fused Q/K/V projection ----------------
// C = x(2048x128) @ W(128x1024); blockIdx.z selects {Wq,Wk,Wv}; out permuted [b][h][t][e].
// As stored TRANSPOSED [k][r] so both fragments read as ds_read_b128.
__global__ __launch_bounds__(256)
void proj3_kernel(const float* __restrict__ A,
                  const float* __restrict__ Wq, const float* __restrict__ Wk,
                  const float* __restrict__ Wv,
                  float* __restrict__ outbase, float scale) {
  const float* W = (blockIdx.z == 0) ? Wq : (blockIdx.z == 1) ? Wk : Wv;
  float sc = (blockIdx.z == 2) ? 1.0f : scale;
  float* out = outbase + (size_t)blockIdx.z * (size_t)B_ * H_ * T_ * E_;

  __shared__ float As[64][68];   // [k][r], 272B row stride (16B aligned)
  __shared__ float Bs[64][68];   // [k][n]
  int tid = threadIdx.x;
  int tm = tid >> 4, tn = tid & 15;
  int row0 = blockIdx.x * 64;
  int col0 = blockIdx.y * 64;
  float acc[4][4] = {};
  for (int kk = 0; kk < 128; kk += 64) {
#pragma unroll
    for (int l = 0; l < 4; ++l) {
      int idx = tid + l * 256;
      int r = idx >> 4, c4 = idx & 15;
      float4 v = *(const float4*)(A + (size_t)(row0 + r) * 128 + kk + c4 * 4);
      As[c4 * 4 + 0][r] = v.x; As[c4 * 4 + 1][r] = v.y;
      As[c4 * 4 + 2][r] = v.z; As[c4 * 4 + 3][r] = v.w;
    }
#pragma unroll
    for (int l = 0; l < 4; ++l) {
      int idx = tid + l * 256;
      int r = idx >> 4, c4 = idx & 15;
      float4 v = *(const float4*)(W + (size_t)(kk + r) * 1024 + col0 + c4 * 4);
      Bs[r][c4 * 4 + 0] = v.x; Bs[r][c4 * 4 + 1] = v.y;
      Bs[r][c4 * 4 + 2] = v.z; Bs[r][c4 * 4 + 3] = v.w;
    }
    __syncthreads();
#pragma unroll 8
    for (int k2 = 0; k2 < 64; ++k2) {
      float4 a4 = *(const float4*)&As[k2][tm * 4];
      float4 b4 = *(const float4*)&Bs[k2][tn * 4];
      float av[4] = {a4.x, a4.y, a4.z, a4.w};
      float bv[4] = {b4.x, b4.y, b4.z, b4.w};
#pragma unroll
      for (int ii = 0; ii < 4; ++ii)
#pragma unroll
        for (int jj = 0; jj < 4; ++jj)
          acc[ii][jj] = fmaf(av[ii], bv[jj], acc[ii][jj]);
    }
    __syncthreads();
  }
#pragma unroll
  for (int ii = 0; ii < 4; ++ii) {
    int row = row0 + tm * 4 + ii;
    int bb = row >> 10, tt = row & 1023;
#pragma unroll
    for (int jj = 0; jj < 4; ++jj) {
      int col = col0 + tn * 4 + jj;
      int hh = col >> 7, ee = col & 127;
      out[(((size_t)bb * H_ + hh) * T_ + tt) * E_ + ee] = acc[ii][jj] * sc;
    }
  }
}

// ---------------- kernel 2: per-token hypernet + points + direct bucketed entries ----------------
__global__ __launch_bounds__(64)
void token_kernel(const float* __restrict__ x,
                  const float* __restrict__ Wp1, const float* __restrict__ bp1,
                  const float* __restrict__ Wp2, const float* __restrict__ bp2,
                  const float* __restrict__ mv,
                  int2* __restrict__ entries, int* __restrict__ cnt) {
  int blk = blockIdx.x;            // b*T + t
  int t = blk & 1023;
  int lane = threadIdx.x;

  __shared__ float xs[E_];
  __shared__ float hs[HID_];
  __shared__ float ps[24];
  __shared__ float m0s[KMIX], m1s[KMIX], sgs[KMIX];
  __shared__ int   fl0s[KMIX], fl1s[KMIX], b0s[KMIX], b1s[KMIX];
  __shared__ int   cs[NPTS_];
  __shared__ float mvs[KMIX];

  xs[lane]      = x[(size_t)blk * E_ + lane];
  xs[lane + 64] = x[(size_t)blk * E_ + lane + 64];
  if (lane < KMIX) mvs[lane] = mv[lane];
  __syncthreads();

  {
    float acc = bp1[lane];
    for (int c = 0; c < E_; ++c) acc = fmaf(xs[c], Wp1[c * HID_ + lane], acc);
    hs[lane] = fmaxf(acc, 0.f);
  }
  __syncthreads();

  if (lane < 24) {
    float p = bp2[lane];
    for (int jj = 0; jj < HID_; ++jj) p = fmaf(hs[jj], Wp2[jj * 24 + lane], p);
    ps[lane] = p;
  }
  __syncthreads();

  if (lane < KMIX) {
    float m0 = ps[2 * lane] + (float)t;
    float m1 = ps[2 * lane + 1] + (float)t;
    if (m1 > m0) { float tmp = m0; m0 = m1; m1 = tmp; }   // _flip
    m0 = fminf(fmaxf(m0, 0.f), (float)(T_ - 1));
    m1 = fminf(fmaxf(m1, 0.f), (float)(T_ - 1));
    float sr = ps[16 + lane] + 2.0f;                       // SIGMA_BOOST
    float sig = fmaxf(sr, 0.f) + log1pf(expf(-fabsf(sr))) + 0.01f;  // softplus + MIN_SIGMA
    m0s[lane] = m0; m1s[lane] = m1; sgs[lane] = sig;
    int f0 = (int)floorf(m0), f1 = (int)floorf(m1);
    fl0s[lane] = f0; fl1s[lane] = f1;
    b0s[lane] = min(max(f0 - 1, 0), T_ - 2);
    b1s[lane] = min(max(f1 - 1, 0), T_ - 2);
  }
  __syncthreads();

  // one point per lane: k = lane>>3, slot = lane&7: [c0..c3, g0,g1, l0,l1]
  int k = lane >> 3, s = lane & 7;
  int i, j;
  if (s < 4) {
    i = min(fl0s[k] + (s >> 1), T_ - 1);
    j = min(fl1s[k] + (s & 1), T_ - 1);
  } else if (s < 6) {
    uint32_t base = ((((uint32_t)blk) * 8u + (uint32_t)k) * 2u + (uint32_t)(s - 4)) * 2u;
    i = (int)(rand_bits32((uint32_t)KG_, (uint32_t)(KG_ >> 32), base + 0u) & 1023u);
    j = (int)(rand_bits32((uint32_t)KG_, (uint32_t)(KG_ >> 32), base + 1u) & 1023u);
  } else {
    uint32_t base = ((((uint32_t)blk) * 8u + (uint32_t)k) * 2u + (uint32_t)(s - 6)) * 2u;
    i = b0s[k] + (int)(rand_bits32((uint32_t)KN_, (uint32_t)(KN_ >> 32), base + 0u) & 1u);
    j = b1s[k] + (int)(rand_bits32((uint32_t)KN_, (uint32_t)(KN_ >> 32), base + 1u) & 1u);
  }
  if (j > i) { int tmp = i; i = j; j = tmp; }              // _flip on indices
  int code = (i << 10) | j;
  cs[lane] = code;
  __syncthreads();

  bool dup = false;
  for (int m = 0; m < lane; ++m) dup = dup || (cs[m] == code);

  float d[KMIX];
  float fi = (float)i, fj = (float)j;
#pragma unroll
  for (int kk = 0; kk < KMIX; ++kk) {
    float r0 = (fi - m0s[kk]) / sgs[kk];
    float r1 = (fj - m1s[kk]) / sgs[kk];
    d[kk] = dup ? 0.f : expf(-0.5f * (r0 * r0 + r1 * r1));
  }
  float w = 0.f;
#pragma unroll
  for (int kk = 0; kk < KMIX; ++kk) {
    float ssum = d[kk];
#pragma unroll
    for (int off = 32; off > 0; off >>= 1) ssum += __shfl_xor(ssum, off, 64);
    w += mvs[kk] * (d[kk] / ssum);
  }
  if (w != 0.f) {
    int key = ((blk >> 10) << 10) | i;    // b*1024 + i
    int pos = atomicAdd(&cnt[key], 1);
    if (pos < CAP) entries[(size_t)key * CAP + pos] = make_int2(j, __float_as_int(w));
  }
}

// ---------------- kernel 3: gather attention (block per row, wave per head, half-wave per entry) ----------------
__global__ __launch_bounds__(512)
void gather_kernel(const int2* __restrict__ entries, const int* __restrict__ cnt,
                   const float* __restrict__ Qw, const float* __restrict__ Kw,
                   const float* __restrict__ Vw, float* __restrict__ att) {
  int bid = blockIdx.x;
  int key = ((bid & 7) << 8) | (bid >> 3);   // XCD swizzle: 2048 = 8 XCDs * 256 contiguous rows
  int b = key >> 10, i = key & 1023;
  int h = threadIdx.x >> 6, lane = threadIdx.x & 63;
  int half = lane >> 5, l5 = lane & 31;
  int n = min(cnt[key], CAP);
  const int2* ebase = entries + (size_t)key * CAP;

  const float* Qrow = Qw + (((size_t)b * H_ + h) * T_ + i) * E_;
  const float* Kh = Kw + ((size_t)b * H_ + h) * (size_t)T_ * E_;
  const float* Vh = Vw + ((size_t)b * H_ + h) * (size_t)T_ * E_;
  float4 q = *(const float4*)(Qrow + l5 * 4);
  float4 acc = {0.f, 0.f, 0.f, 0.f};

  for (int e = half; e < n; e += 2) {        // half 0: even entries, half 1: odd entries
    int2 ent = ebase[e];
    int j = ent.x;
    float wgt = __int_as_float(ent.y);
    float4 kv = *(const float4*)(Kh + (size_t)j * E_ + l5 * 4);
    float p = q.x * kv.x + q.y * kv.y + q.z * kv.z + q.w * kv.w;
    p += __shfl_xor(p, 16, 64);
    p += __shfl_xor(p, 8, 64);
    p += __shfl_xor(p, 4, 64);
    p += __shfl_xor(p, 2, 64);
    p += __shfl_xor(p, 1, 64);               // 5-step reduce, stays within 32-lane half
    float val = p * wgt;
    float4 v = *(const float4*)(Vh + (size_t)j * E_ + l5 * 4);
    acc.x = fmaf(val, v.x, acc.x);
    acc.y = fmaf(val, v.y, acc.y);
    acc.z = fmaf(val, v.z, acc.z);
    acc.w = fmaf(val, v.w, acc.w);
  }
  // combine the two halves (same output cols)
  acc.x += __shfl_xor(acc.x, 32, 64);
  acc.y += __shfl_xor(acc.y, 32, 64);
  acc.z += __shfl_xor(acc.z, 32, 64);
  acc.w += __shfl_xor(acc.w, 32, 64);
  if (half == 0)
    *(float4*)(att + (((size_t)b * H_ + h) * T_ + i) * E_ + l5 * 4) = acc;
}

// ---------------- kernel 4: split-K output projection (z = head = K-chunk of 128) ----------------
__global__ __launch_bounds__(256)
void outproj_split_kernel(const float* __restrict__ att, const float* __restrict__ Wu,
                          float* __restrict__ partials) {
  __shared__ float As[64][68];   // [k][r] transposed
  __shared__ float Bs[64][68];
  int tid = threadIdx.x;
  int tm = tid >> 4, tn = tid & 15;
  int row0 = blockIdx.x * 64;   // rows = b*T + t
  int col0 = blockIdx.y * 64;   // 0 or 64
  int hh = blockIdx.z;          // head = K-chunk
  float acc[4][4] = {};
  for (int step = 0; step < 2; ++step) {
    int e0 = step * 64;
#pragma unroll
    for (int l = 0; l < 4; ++l) {
      int idx = tid + l * 256;
      int r = idx >> 4, c4 = idx & 15;
      int row = row0 + r;
      int bb = row >> 10, tt = row & 1023;
      float4 v = *(const float4*)(att + (((size_t)bb * H_ + hh) * T_ + tt) * E_ + e0 + c4 * 4);
      As[c4 * 4 + 0][r] = v.x; As[c4 * 4 + 1][r] = v.y;
      As[c4 * 4 + 2][r] = v.z; As[c4 * 4 + 3][r] = v.w;
    }
#pragma unroll
    for (int l = 0; l < 4; ++l) {
      int idx = tid + l * 256;
      int r = idx >> 4, c4 = idx & 15;
      float4 v = *(const float4*)(Wu + (size_t)(hh * 128 + e0 + r) * 128 + col0 + c4 * 4);
      Bs[r][c4 * 4 + 0] = v.x; Bs[r][c4 * 4 + 1] = v.y;
      Bs[r][c4 * 4 + 2] = v.z; Bs[r][c4 * 4 + 3] = v.w;
    }
    __syncthreads();
#pragma unroll 8
    for (int k2 = 0; k2 < 64; ++k2) {
      float4 a4 = *(const float4*)&As[k2][tm * 4];
      float4 b4 = *(const float4*)&Bs[k2][tn * 4];
      float av[4] = {a4.x, a4.y, a4.z, a4.w};
      float bv[4] = {b4.x, b4.y, b4.z, b4.w};
#pragma unroll
      for (int ii = 0; ii < 4; ++ii)
#pragma unroll
        for (int jj = 0; jj < 4; ++jj)
          acc[ii][jj] = fmaf(av[ii], bv[jj], acc[ii][jj]);
    }
    __syncthreads();
  }
  float* pbase = partials + (size_t)hh * NROWS * 128;
#pragma unroll
  for (int ii = 0; ii < 4; ++ii) {
    int row = row0 + tm * 4 + ii;
#pragma unroll
    for (int jj = 0; jj < 4; ++jj) {
      int col = col0 + tn * 4 + jj;
      pbase[(size_t)row * 128 + col] = acc[ii][jj];
    }
  }
}

// ---------------- kernel 5: reduce 8 partials + bias ----------------
__global__ __launch_bounds__(256)
void reduce_kernel(const float* __restrict__ partials, const float* __restrict__ bu,
                   float* __restrict__ out) {
  int idx = blockIdx.x * 256 + threadIdx.x;    // row*128 + col, 262144 total
  int col = idx & 127;
  float s = bu[col];
#pragma unroll
  for (int z = 0; z < H_; ++z)
    s += partials[(size_t)z * NROWS * 128 + idx];
  out[idx] = s;
}

extern "C" void kernel_launch(void* const* d_in, const int* in_sizes, int n_in,
                              void* d_out, int out_size, void* d_ws, size_t ws_size,
                              hipStream_t stream) {
  const float* x   = (const float*)d_in[0];
  const float* Wq  = (const float*)d_in[1];
  const float* Wk  = (const float*)d_in[2];
  const float* Wv  = (const float*)d_in[3];
  const float* Wu  = (const float*)d_in[4];
  const float* bu  = (const float*)d_in[5];
  const float* Wp1 = (const float*)d_in[6];
  const float* bp1 = (const float*)d_in[7];
  const float* Wp2 = (const float*)d_in[8];
  const float* bp2 = (const float*)d_in[9];
  const float* mv  = (const float*)d_in[10];
  float* out = (float*)d_out;

  const size_t NF = (size_t)B_ * H_ * T_ * E_;    // 2097152 floats per tensor
  float* Qw       = (float*)d_ws;                 // Q,K,V contiguous (proj3 indexes by z)
  float* Kw       = Qw + NF;
  float* Vw       = Kw + NF;
  float* att      = Vw + NF;
  int*   cnt      = (int*)(att + NF);             // 2048 ints
  int2*  entries  = (int2*)(cnt + NROWS);         // 2048 * CAP * 8B = 5.24 MB
  float* partials = (float*)(entries + (size_t)NROWS * CAP);  // 8 MB

  const float scale = 0.29730177875068026f;       // 128^-0.25

  hipMemsetAsync(cnt, 0, NROWS * sizeof(int), stream);
  proj3_kernel<<<dim3(32, 16, 3), 256, 0, stream>>>(x, Wq, Wk, Wv, Qw, scale);
  token_kernel<<<NROWS, 64, 0, stream>>>(x, Wp1, bp1, Wp2, bp2, mv, entries, cnt);
  gather_kernel<<<NROWS, 512, 0, stream>>>(entries, cnt, Qw, Kw, Vw, att);
  outproj_split_kernel<<<dim3(32, 2, 8), 256, 0, stream>>>(att, Wu, partials);
  reduce_kernel<<<NROWS * 128 / 256, 256, 0, stream>>>(partials, bu, out);
}

// Round 12
// 145.544 us; speedup vs baseline: 2.6077x; 1.0230x over previous
//
#include <hip/hip_runtime.h>
#include <stdint.h>

#define B_ 2
#define T_ 1024
#define E_ 128
#define H_ 8
#define KMIX 8
#define NPTS_ 64
#define HID_ 64
#define NROWS (B_ * T_)              // 2048 row buckets
#define CAP 320                      // max entries per row bucket (audit: worst ~250)

// ---------------- bf16 helpers (RNE) ----------------
__device__ __forceinline__ unsigned short f2bf(float f) {
  uint32_t u = __float_as_uint(f);
  return (unsigned short)((u + 0x7FFFu + ((u >> 16) & 1u)) >> 16);
}
__device__ __forceinline__ float bf2f(unsigned short s) {
  return __uint_as_float(((uint32_t)s) << 16);
}

// ---------------- threefry2x32 (JAX partitionable stream) ----------------
__device__ __forceinline__ void tf2x32(uint32_t k0, uint32_t k1,
                                       uint32_t x0, uint32_t x1,
                                       uint32_t& o0, uint32_t& o1) {
  uint32_t ks2 = k0 ^ k1 ^ 0x1BD11BDAu;
  x0 += k0; x1 += k1;
#define RND(r) { x0 += x1; x1 = (x1 << (r)) | (x1 >> (32 - (r))); x1 ^= x0; }
  RND(13) RND(15) RND(26) RND(6)
  x0 += k1;  x1 += ks2 + 1u;
  RND(17) RND(29) RND(16) RND(24)
  x0 += ks2; x1 += k0 + 2u;
  RND(13) RND(15) RND(26) RND(6)
  x0 += k0;  x1 += k1 + 3u;
  RND(17) RND(29) RND(16) RND(24)
  x0 += k1;  x1 += ks2 + 4u;
  RND(13) RND(15) RND(26) RND(6)
  x0 += ks2; x1 += k0 + 5u;
#undef RND
  o0 = x0; o1 = x1;
}

// compile-time variant: the two randint lower keys are constants of key(1)
constexpr uint64_t tf_ce(uint32_t k0, uint32_t k1, uint32_t x0, uint32_t x1) {
  uint32_t ks2 = k0 ^ k1 ^ 0x1BD11BDAu;
  x0 += k0; x1 += k1;
#define RND(r) { x0 += x1; x1 = (x1 << (r)) | (x1 >> (32 - (r))); x1 ^= x0; }
  RND(13) RND(15) RND(26) RND(6)
  x0 += k1;  x1 += ks2 + 1u;
  RND(17) RND(29) RND(16) RND(24)
  x0 += ks2; x1 += k0 + 2u;
  RND(13) RND(15) RND(26) RND(6)
  x0 += k0;  x1 += k1 + 3u;
  RND(17) RND(29) RND(16) RND(24)
  x0 += k1;  x1 += ks2 + 4u;
  RND(13) RND(15) RND(26) RND(6)
  x0 += ks2; x1 += k0 + 5u;
#undef RND
  return ((uint64_t)x1 << 32) | x0;
}
constexpr uint64_t lower_key_ce(uint32_t which) {
  uint64_t a = tf_ce(0u, 1u, 0u, which);                       // split(key(1))[which]
  return tf_ce((uint32_t)a, (uint32_t)(a >> 32), 0u, 1u);      // split(that)[1]
}
constexpr uint64_t KG_ = lower_key_ce(0);   // glob randint lower key
constexpr uint64_t KN_ = lower_key_ce(1);   // loc randint lower key

__device__ __forceinline__ uint32_t rand_bits32(uint32_t k0, uint32_t k1, uint32_t f) {
  uint32_t o0, o1;
  tf2x32(k0, k1, 0u, f, o0, o1);
  return o0 ^ o1;                           // partitionable 32-bit draw
}

// ---------------- kernel 1: fused Q/K/V projection -> bf16 ----------------
// C = x(2048x128) @ W(128x1024); blockIdx.z selects {Wq,Wk,Wv}; out bf16 permuted [b][h][t][e].
__global__ __launch_bounds__(256)
void proj3_kernel(const float* __restrict__ A,
                  const float* __restrict__ Wq, const float* __restrict__ Wk,
                  const float* __restrict__ Wv,
                  unsigned short* __restrict__ outbase, float scale) {
  const float* W = (blockIdx.z == 0) ? Wq : (blockIdx.z == 1) ? Wk : Wv;
  float sc = (blockIdx.z == 2) ? 1.0f : scale;
  unsigned short* out = outbase + (size_t)blockIdx.z * (size_t)B_ * H_ * T_ * E_;

  __shared__ float As[64][68];   // [k][r] transposed -> ds_read_b128 fragments
  __shared__ float Bs[64][68];   // [k][n]
  int tid = threadIdx.x;
  int tm = tid >> 4, tn = tid & 15;
  int row0 = blockIdx.x * 64;
  int col0 = blockIdx.y * 64;
  float acc[4][4] = {};
  for (int kk = 0; kk < 128; kk += 64) {
#pragma unroll
    for (int l = 0; l < 4; ++l) {
      int idx = tid + l * 256;
      int r = idx >> 4, c4 = idx & 15;
      float4 v = *(const float4*)(A + (size_t)(row0 + r) * 128 + kk + c4 * 4);
      As[c4 * 4 + 0][r] = v.x; As[c4 * 4 + 1][r] = v.y;
      As[c4 * 4 + 2][r] = v.z; As[c4 * 4 + 3][r] = v.w;
    }
#pragma unroll
    for (int l = 0; l < 4; ++l) {
      int idx = tid + l * 256;
      int r = idx >> 4, c4 = idx & 15;
      float4 v = *(const float4*)(W + (size_t)(kk + r) * 1024 + col0 + c4 * 4);
      Bs[r][c4 * 4 + 0] = v.x; Bs[r][c4 * 4 + 1] = v.y;
      Bs[r][c4 * 4 + 2] = v.z; Bs[r][c4 * 4 + 3] = v.w;
    }
    __syncthreads();
#pragma unroll 8
    for (int k2 = 0; k2 < 64; ++k2) {
      float4 a4 = *(const float4*)&As[k2][tm * 4];
      float4 b4 = *(const float4*)&Bs[k2][tn * 4];
      float av[4] = {a4.x, a4.y, a4.z, a4.w};
      float bv[4] = {b4.x, b4.y, b4.z, b4.w};
#pragma unroll
      for (int ii = 0; ii < 4; ++ii)
#pragma unroll
        for (int jj = 0; jj < 4; ++jj)
          acc[ii][jj] = fmaf(av[ii], bv[jj], acc[ii][jj]);
    }
    __syncthreads();
  }
  // 64-col tile lies within one head (head width 128, col0 multiple of 64)
  int hh = col0 >> 7;
  int ee0 = (col0 & 127) + tn * 4;
#pragma unroll
  for (int ii = 0; ii < 4; ++ii) {
    int row = row0 + tm * 4 + ii;
    int bb = row >> 10, tt = row & 1023;
    ushort4 st;
    st.x = f2bf(acc[ii][0] * sc);
    st.y = f2bf(acc[ii][1] * sc);
    st.z = f2bf(acc[ii][2] * sc);
    st.w = f2bf(acc[ii][3] * sc);
    *(ushort4*)(out + (((size_t)bb * H_ + hh) * T_ + tt) * E_ + ee0) = st;
  }
}

// ---------------- kernel 2: per-token hypernet + points + direct bucketed entries ----------------
__global__ __launch_bounds__(64)
void token_kernel(const float* __restrict__ x,
                  const float* __restrict__ Wp1, const float* __restrict__ bp1,
                  const float* __restrict__ Wp2, const float* __restrict__ bp2,
                  const float* __restrict__ mv,
                  int2* __restrict__ entries, int* __restrict__ cnt) {
  int blk = blockIdx.x;            // b*T + t
  int t = blk & 1023;
  int lane = threadIdx.x;

  __shared__ float xs[E_];
  __shared__ float hs[HID_];
  __shared__ float ps[24];
  __shared__ float m0s[KMIX], m1s[KMIX], sgs[KMIX];
  __shared__ int   fl0s[KMIX], fl1s[KMIX], b0s[KMIX], b1s[KMIX];
  __shared__ int   cs[NPTS_];
  __shared__ float mvs[KMIX];

  xs[lane]      = x[(size_t)blk * E_ + lane];
  xs[lane + 64] = x[(size_t)blk * E_ + lane + 64];
  if (lane < KMIX) mvs[lane] = mv[lane];
  __syncthreads();

  {
    float acc = bp1[lane];
    for (int c = 0; c < E_; ++c) acc = fmaf(xs[c], Wp1[c * HID_ + lane], acc);
    hs[lane] = fmaxf(acc, 0.f);
  }
  __syncthreads();

  if (lane < 24) {
    float p = bp2[lane];
    for (int jj = 0; jj < HID_; ++jj) p = fmaf(hs[jj], Wp2[jj * 24 + lane], p);
    ps[lane] = p;
  }
  __syncthreads();

  if (lane < KMIX) {
    float m0 = ps[2 * lane] + (float)t;
    float m1 = ps[2 * lane + 1] + (float)t;
    if (m1 > m0) { float tmp = m0; m0 = m1; m1 = tmp; }   // _flip
    m0 = fminf(fmaxf(m0, 0.f), (float)(T_ - 1));
    m1 = fminf(fmaxf(m1, 0.f), (float)(T_ - 1));
    float sr = ps[16 + lane] + 2.0f;                       // SIGMA_BOOST
    float sig = fmaxf(sr, 0.f) + log1pf(expf(-fabsf(sr))) + 0.01f;  // softplus + MIN_SIGMA
    m0s[lane] = m0; m1s[lane] = m1; sgs[lane] = sig;
    int f0 = (int)floorf(m0), f1 = (int)floorf(m1);
    fl0s[lane] = f0; fl1s[lane] = f1;
    b0s[lane] = min(max(f0 - 1, 0), T_ - 2);
    b1s[lane] = min(max(f1 - 1, 0), T_ - 2);
  }
  __syncthreads();

  // one point per lane: k = lane>>3, slot = lane&7: [c0..c3, g0,g1, l0,l1]
  int k = lane >> 3, s = lane & 7;
  int i, j;
  if (s < 4) {
    i = min(fl0s[k] + (s >> 1), T_ - 1);
    j = min(fl1s[k] + (s & 1), T_ - 1);
  } else if (s < 6) {
    uint32_t base = ((((uint32_t)blk) * 8u + (uint32_t)k) * 2u + (uint32_t)(s - 4)) * 2u;
    i = (int)(rand_bits32((uint32_t)KG_, (uint32_t)(KG_ >> 32), base + 0u) & 1023u);
    j = (int)(rand_bits32((uint32_t)KG_, (uint32_t)(KG_ >> 32), base + 1u) & 1023u);
  } else {
    uint32_t base = ((((uint32_t)blk) * 8u + (uint32_t)k) * 2u + (uint32_t)(s - 6)) * 2u;
    i = b0s[k] + (int)(rand_bits32((uint32_t)KN_, (uint32_t)(KN_ >> 32), base + 0u) & 1u);
    j = b1s[k] + (int)(rand_bits32((uint32_t)KN_, (uint32_t)(KN_ >> 32), base + 1u) & 1u);
  }
  if (j > i) { int tmp = i; i = j; j = tmp; }              // _flip on indices
  int code = (i << 10) | j;
  cs[lane] = code;
  __syncthreads();

  bool dup = false;
  for (int m = 0; m < lane; ++m) dup = dup || (cs[m] == code);

  float d[KMIX];
  float fi = (float)i, fj = (float)j;
#pragma unroll
  for (int kk = 0; kk < KMIX; ++kk) {
    float r0 = (fi - m0s[kk]) / sgs[kk];
    float r1 = (fj - m1s[kk]) / sgs[kk];
    d[kk] = dup ? 0.f : expf(-0.5f * (r0 * r0 + r1 * r1));
  }
  float w = 0.f;
#pragma unroll
  for (int kk = 0; kk < KMIX; ++kk) {
    float ssum = d[kk];
#pragma unroll
    for (int off = 32; off > 0; off >>= 1) ssum += __shfl_xor(ssum, off, 64);
    w += mvs[kk] * (d[kk] / ssum);
  }
  if (w != 0.f) {
    int key = ((blk >> 10) << 10) | i;    // b*1024 + i
    int pos = atomicAdd(&cnt[key], 1);
    if (pos < CAP) entries[(size_t)key * CAP + pos] = make_int2(j, __float_as_int(w));
  }
}

// ---------------- kernel 3: gather attention (bf16 Q/K/V; block per row, wave per head, half-wave per entry) ----------------
__global__ __launch_bounds__(512)
void gather_kernel(const int2* __restrict__ entries, const int* __restrict__ cnt,
                   const unsigned short* __restrict__ Qb, const unsigned short* __restrict__ Kb,
                   const unsigned short* __restrict__ Vb, float* __restrict__ att) {
  int bid = blockIdx.x;
  int key = ((bid & 7) << 8) | (bid >> 3);   // XCD swizzle: 2048 = 8 XCDs * 256 contiguous rows
  int b = key >> 10, i = key & 1023;
  int h = threadIdx.x >> 6, lane = threadIdx.x & 63;
  int half = lane >> 5, l5 = lane & 31;
  int n = min(cnt[key], CAP);
  const int2* ebase = entries + (size_t)key * CAP;

  const unsigned short* Qrow = Qb + (((size_t)b * H_ + h) * T_ + i) * E_;
  const unsigned short* Kh = Kb + ((size_t)b * H_ + h) * (size_t)T_ * E_;
  const unsigned short* Vh = Vb + ((size_t)b * H_ + h) * (size_t)T_ * E_;
  ushort4 qu = *(const ushort4*)(Qrow + l5 * 4);
  float4 q = {bf2f(qu.x), bf2f(qu.y), bf2f(qu.z), bf2f(qu.w)};
  float4 acc = {0.f, 0.f, 0.f, 0.f};

  for (int e = half; e < n; e += 2) {        // half 0: even entries, half 1: odd entries
    int2 ent = ebase[e];
    int j = ent.x;
    float wgt = __int_as_float(ent.y);
    ushort4 ku = *(const ushort4*)(Kh + (size_t)j * E_ + l5 * 4);
    float p = q.x * bf2f(ku.x) + q.y * bf2f(ku.y) + q.z * bf2f(ku.z) + q.w * bf2f(ku.w);
    p += __shfl_xor(p, 16, 64);
    p += __shfl_xor(p, 8, 64);
    p += __shfl_xor(p, 4, 64);
    p += __shfl_xor(p, 2, 64);
    p += __shfl_xor(p, 1, 64);               // 5-step reduce, stays within 32-lane half
    float val = p * wgt;
    ushort4 vu = *(const ushort4*)(Vh + (size_t)j * E_ + l5 * 4);
    acc.x = fmaf(val, bf2f(vu.x), acc.x);
    acc.y = fmaf(val, bf2f(vu.y), acc.y);
    acc.z = fmaf(val, bf2f(vu.z), acc.z);
    acc.w = fmaf(val, bf2f(vu.w), acc.w);
  }
  // combine the two halves (same output cols)
  acc.x += __shfl_xor(acc.x, 32, 64);
  acc.y += __shfl_xor(acc.y, 32, 64);
  acc.z += __shfl_xor(acc.z, 32, 64);
  acc.w += __shfl_xor(acc.w, 32, 64);
  if (half == 0)
    *(float4*)(att + (((size_t)b * H_ + h) * T_ + i) * E_ + l5 * 4) = acc;
}

// ---------------- kernel 4: split-K output projection (z = head = K-chunk of 128) ----------------
__global__ __launch_bounds__(256)
void outproj_split_kernel(const float* __restrict__ att, const float* __restrict__ Wu,
                          float* __restrict__ partials) {
  __shared__ float As[64][68];   // [k][r] transposed
  __shared__ float Bs[64][68];
  int tid = threadIdx.x;
  int tm = tid >> 4, tn = tid & 15;
  int row0 = blockIdx.x * 64;   // rows = b*T + t
  int col0 = blockIdx.y * 64;   // 0 or 64
  int hh = blockIdx.z;          // head = K-chunk
  float acc[4][4] = {};
  for (int step = 0; step < 2; ++step) {
    int e0 = step * 64;
#pragma unroll
    for (int l = 0; l < 4; ++l) {
      int idx = tid + l * 256;
      int r = idx >> 4, c4 = idx & 15;
      int row = row0 + r;
      int bb = row >> 10, tt = row & 1023;
      float4 v = *(const float4*)(att + (((size_t)bb * H_ + hh) * T_ + tt) * E_ + e0 + c4 * 4);
      As[c4 * 4 + 0][r] = v.x; As[c4 * 4 + 1][r] = v.y;
      As[c4 * 4 + 2][r] = v.z; As[c4 * 4 + 3][r] = v.w;
    }
#pragma unroll
    for (int l = 0; l < 4; ++l) {
      int idx = tid + l * 256;
      int r = idx >> 4, c4 = idx & 15;
      float4 v = *(const float4*)(Wu + (size_t)(hh * 128 + e0 + r) * 128 + col0 + c4 * 4);
      Bs[r][c4 * 4 + 0] = v.x; Bs[r][c4 * 4 + 1] = v.y;
      Bs[r][c4 * 4 + 2] = v.z; Bs[r][c4 * 4 + 3] = v.w;
    }
    __syncthreads();
#pragma unroll 8
    for (int k2 = 0; k2 < 64; ++k2) {
      float4 a4 = *(const float4*)&As[k2][tm * 4];
      float4 b4 = *(const float4*)&Bs[k2][tn * 4];
      float av[4] = {a4.x, a4.y, a4.z, a4.w};
      float bv[4] = {b4.x, b4.y, b4.z, b4.w};
#pragma unroll
      for (int ii = 0; ii < 4; ++ii)
#pragma unroll
        for (int jj = 0; jj < 4; ++jj)
          acc[ii][jj] = fmaf(av[ii], bv[jj], acc[ii][jj]);
    }
    __syncthreads();
  }
  float* pbase = partials + (size_t)hh * NROWS * 128;
#pragma unroll
  for (int ii = 0; ii < 4; ++ii) {
    int row = row0 + tm * 4 + ii;
#pragma unroll
    for (int jj = 0; jj < 4; ++jj) {
      int col = col0 + tn * 4 + jj;
      pbase[(size_t)row * 128 + col] = acc[ii][jj];
    }
  }
}

// ---------------- kernel 5: reduce 8 partials + bias ----------------
__global__ __launch_bounds__(256)
void reduce_kernel(const float* __restrict__ partials, const float* __restrict__ bu,
                   float* __restrict__ out) {
  int idx = blockIdx.x * 256 + threadIdx.x;    // row*128 + col, 262144 total
  int col = idx & 127;
  float s = bu[col];
#pragma unroll
  for (int z = 0; z < H_; ++z)
    s += partials[(size_t)z * NROWS * 128 + idx];
  out[idx] = s;
}

extern "C" void kernel_launch(void* const* d_in, const int* in_sizes, int n_in,
                              void* d_out, int out_size, void* d_ws, size_t ws_size,
                              hipStream_t stream) {
  const float* x   = (const float*)d_in[0];
  const float* Wq  = (const float*)d_in[1];
  const float* Wk  = (const float*)d_in[2];
  const float* Wv  = (const float*)d_in[3];
  const float* Wu  = (const float*)d_in[4];
  const float* bu  = (const float*)d_in[5];
  const float* Wp1 = (const float*)d_in[6];
  const float* bp1 = (const float*)d_in[7];
  const float* Wp2 = (const float*)d_in[8];
  const float* bp2 = (const float*)d_in[9];
  const float* mv  = (const float*)d_in[10];
  float* out = (float*)d_out;

  const size_t NF = (size_t)B_ * H_ * T_ * E_;    // 2097152 elems per tensor
  unsigned short* Qb = (unsigned short*)d_ws;     // Q,K,V contiguous bf16 (proj3 indexes by z): 12 MB
  unsigned short* Kb = Qb + NF;
  unsigned short* Vb = Kb + NF;
  float* att      = (float*)(Vb + NF);            // 8 MB fp32
  int*   cnt      = (int*)(att + NF);             // 2048 ints
  int2*  entries  = (int2*)(cnt + NROWS);         // 2048 * CAP * 8B = 5.24 MB
  float* partials = (float*)(entries + (size_t)NROWS * CAP);  // 8 MB

  const float scale = 0.29730177875068026f;       // 128^-0.25

  hipMemsetAsync(cnt, 0, NROWS * sizeof(int), stream);
  proj3_kernel<<<dim3(32, 16, 3), 256, 0, stream>>>(x, Wq, Wk, Wv, Qb, scale);
  token_kernel<<<NROWS, 64, 0, stream>>>(x, Wp1, bp1, Wp2, bp2, mv, entries, cnt);
  gather_kernel<<<NROWS, 512, 0, stream>>>(entries, cnt, Qb, Kb, Vb, att);
  outproj_split_kernel<<<dim3(32, 2, 8), 256, 0, stream>>>(att, Wu, partials);
  reduce_kernel<<<NROWS * 128 / 256, 256, 0, stream>>>(partials, bu, out);
}

// Round 13
// 145.203 us; speedup vs baseline: 2.6138x; 1.0023x over previous
//
#include <hip/hip_runtime.h>
#include <stdint.h>

#define B_ 2
#define T_ 1024
#define E_ 128
#define H_ 8
#define KMIX 8
#define NPTS_ 64
#define HID_ 64
#define NROWS (B_ * T_)              // 2048 row buckets
#define CAP 320                      // max entries per row bucket (audit: worst ~250)

// ---------------- bf16 helpers (RNE) ----------------
__device__ __forceinline__ unsigned short f2bf(float f) {
  uint32_t u = __float_as_uint(f);
  return (unsigned short)((u + 0x7FFFu + ((u >> 16) & 1u)) >> 16);
}
__device__ __forceinline__ float bf2f(unsigned short s) {
  return __uint_as_float(((uint32_t)s) << 16);
}
// unpack uint32 holding 2 bf16 -> 2 floats (hi half is a float bit-pattern already)
__device__ __forceinline__ void bfpair(uint32_t u, float& lo, float& hi) {
  lo = __uint_as_float(u << 16);
  hi = __uint_as_float(u & 0xFFFF0000u);
}

// ---------------- threefry2x32 (JAX partitionable stream) ----------------
__device__ __forceinline__ void tf2x32(uint32_t k0, uint32_t k1,
                                       uint32_t x0, uint32_t x1,
                                       uint32_t& o0, uint32_t& o1) {
  uint32_t ks2 = k0 ^ k1 ^ 0x1BD11BDAu;
  x0 += k0; x1 += k1;
#define RND(r) { x0 += x1; x1 = (x1 << (r)) | (x1 >> (32 - (r))); x1 ^= x0; }
  RND(13) RND(15) RND(26) RND(6)
  x0 += k1;  x1 += ks2 + 1u;
  RND(17) RND(29) RND(16) RND(24)
  x0 += ks2; x1 += k0 + 2u;
  RND(13) RND(15) RND(26) RND(6)
  x0 += k0;  x1 += k1 + 3u;
  RND(17) RND(29) RND(16) RND(24)
  x0 += k1;  x1 += ks2 + 4u;
  RND(13) RND(15) RND(26) RND(6)
  x0 += ks2; x1 += k0 + 5u;
#undef RND
  o0 = x0; o1 = x1;
}

// compile-time variant: the two randint lower keys are constants of key(1)
constexpr uint64_t tf_ce(uint32_t k0, uint32_t k1, uint32_t x0, uint32_t x1) {
  uint32_t ks2 = k0 ^ k1 ^ 0x1BD11BDAu;
  x0 += k0; x1 += k1;
#define RND(r) { x0 += x1; x1 = (x1 << (r)) | (x1 >> (32 - (r))); x1 ^= x0; }
  RND(13) RND(15) RND(26) RND(6)
  x0 += k1;  x1 += ks2 + 1u;
  RND(17) RND(29) RND(16) RND(24)
  x0 += ks2; x1 += k0 + 2u;
  RND(13) RND(15) RND(26) RND(6)
  x0 += k0;  x1 += k1 + 3u;
  RND(17) RND(29) RND(16) RND(24)
  x0 += k1;  x1 += ks2 + 4u;
  RND(13) RND(15) RND(26) RND(6)
  x0 += ks2; x1 += k0 + 5u;
#undef RND
  return ((uint64_t)x1 << 32) | x0;
}
constexpr uint64_t lower_key_ce(uint32_t which) {
  uint64_t a = tf_ce(0u, 1u, 0u, which);                       // split(key(1))[which]
  return tf_ce((uint32_t)a, (uint32_t)(a >> 32), 0u, 1u);      // split(that)[1]
}
constexpr uint64_t KG_ = lower_key_ce(0);   // glob randint lower key
constexpr uint64_t KN_ = lower_key_ce(1);   // loc randint lower key

__device__ __forceinline__ uint32_t rand_bits32(uint32_t k0, uint32_t k1, uint32_t f) {
  uint32_t o0, o1;
  tf2x32(k0, k1, 0u, f, o0, o1);
  return o0 ^ o1;                           // partitionable 32-bit draw
}

// ---------------- kernel 1: fused Q/K/V projection -> bf16 ----------------
__global__ __launch_bounds__(256)
void proj3_kernel(const float* __restrict__ A,
                  const float* __restrict__ Wq, const float* __restrict__ Wk,
                  const float* __restrict__ Wv,
                  unsigned short* __restrict__ outbase, float scale) {
  const float* W = (blockIdx.z == 0) ? Wq : (blockIdx.z == 1) ? Wk : Wv;
  float sc = (blockIdx.z == 2) ? 1.0f : scale;
  unsigned short* out = outbase + (size_t)blockIdx.z * (size_t)B_ * H_ * T_ * E_;

  __shared__ float As[64][68];   // [k][r] transposed -> ds_read_b128 fragments
  __shared__ float Bs[64][68];   // [k][n]
  int tid = threadIdx.x;
  int tm = tid >> 4, tn = tid & 15;
  int row0 = blockIdx.x * 64;
  int col0 = blockIdx.y * 64;
  float acc[4][4] = {};
  for (int kk = 0; kk < 128; kk += 64) {
#pragma unroll
    for (int l = 0; l < 4; ++l) {
      int idx = tid + l * 256;
      int r = idx >> 4, c4 = idx & 15;
      float4 v = *(const float4*)(A + (size_t)(row0 + r) * 128 + kk + c4 * 4);
      As[c4 * 4 + 0][r] = v.x; As[c4 * 4 + 1][r] = v.y;
      As[c4 * 4 + 2][r] = v.z; As[c4 * 4 + 3][r] = v.w;
    }
#pragma unroll
    for (int l = 0; l < 4; ++l) {
      int idx = tid + l * 256;
      int r = idx >> 4, c4 = idx & 15;
      float4 v = *(const float4*)(W + (size_t)(kk + r) * 1024 + col0 + c4 * 4);
      Bs[r][c4 * 4 + 0] = v.x; Bs[r][c4 * 4 + 1] = v.y;
      Bs[r][c4 * 4 + 2] = v.z; Bs[r][c4 * 4 + 3] = v.w;
    }
    __syncthreads();
#pragma unroll 8
    for (int k2 = 0; k2 < 64; ++k2) {
      float4 a4 = *(const float4*)&As[k2][tm * 4];
      float4 b4 = *(const float4*)&Bs[k2][tn * 4];
      float av[4] = {a4.x, a4.y, a4.z, a4.w};
      float bv[4] = {b4.x, b4.y, b4.z, b4.w};
#pragma unroll
      for (int ii = 0; ii < 4; ++ii)
#pragma unroll
        for (int jj = 0; jj < 4; ++jj)
          acc[ii][jj] = fmaf(av[ii], bv[jj], acc[ii][jj]);
    }
    __syncthreads();
  }
  int hh = col0 >> 7;
  int ee0 = (col0 & 127) + tn * 4;
#pragma unroll
  for (int ii = 0; ii < 4; ++ii) {
    int row = row0 + tm * 4 + ii;
    int bb = row >> 10, tt = row & 1023;
    ushort4 st;
    st.x = f2bf(acc[ii][0] * sc);
    st.y = f2bf(acc[ii][1] * sc);
    st.z = f2bf(acc[ii][2] * sc);
    st.w = f2bf(acc[ii][3] * sc);
    *(ushort4*)(out + (((size_t)bb * H_ + hh) * T_ + tt) * E_ + ee0) = st;
  }
}

// ---------------- kernel 2: per-token hypernet + points + direct bucketed entries ----------------
__global__ __launch_bounds__(64)
void token_kernel(const float* __restrict__ x,
                  const float* __restrict__ Wp1, const float* __restrict__ bp1,
                  const float* __restrict__ Wp2, const float* __restrict__ bp2,
                  const float* __restrict__ mv,
                  int2* __restrict__ entries, int* __restrict__ cnt) {
  int blk = blockIdx.x;            // b*T + t
  int t = blk & 1023;
  int lane = threadIdx.x;

  __shared__ float xs[E_];
  __shared__ float hs[HID_];
  __shared__ float ps[24];
  __shared__ float m0s[KMIX], m1s[KMIX], sgs[KMIX];
  __shared__ int   fl0s[KMIX], fl1s[KMIX], b0s[KMIX], b1s[KMIX];
  __shared__ int   cs[NPTS_];
  __shared__ float mvs[KMIX];

  xs[lane]      = x[(size_t)blk * E_ + lane];
  xs[lane + 64] = x[(size_t)blk * E_ + lane + 64];
  if (lane < KMIX) mvs[lane] = mv[lane];
  __syncthreads();

  {
    float acc = bp1[lane];
    for (int c = 0; c < E_; ++c) acc = fmaf(xs[c], Wp1[c * HID_ + lane], acc);
    hs[lane] = fmaxf(acc, 0.f);
  }
  __syncthreads();

  if (lane < 24) {
    float p = bp2[lane];
    for (int jj = 0; jj < HID_; ++jj) p = fmaf(hs[jj], Wp2[jj * 24 + lane], p);
    ps[lane] = p;
  }
  __syncthreads();

  if (lane < KMIX) {
    float m0 = ps[2 * lane] + (float)t;
    float m1 = ps[2 * lane + 1] + (float)t;
    if (m1 > m0) { float tmp = m0; m0 = m1; m1 = tmp; }   // _flip
    m0 = fminf(fmaxf(m0, 0.f), (float)(T_ - 1));
    m1 = fminf(fmaxf(m1, 0.f), (float)(T_ - 1));
    float sr = ps[16 + lane] + 2.0f;                       // SIGMA_BOOST
    float sig = fmaxf(sr, 0.f) + log1pf(expf(-fabsf(sr))) + 0.01f;  // softplus + MIN_SIGMA
    m0s[lane] = m0; m1s[lane] = m1; sgs[lane] = sig;
    int f0 = (int)floorf(m0), f1 = (int)floorf(m1);
    fl0s[lane] = f0; fl1s[lane] = f1;
    b0s[lane] = min(max(f0 - 1, 0), T_ - 2);
    b1s[lane] = min(max(f1 - 1, 0), T_ - 2);
  }
  __syncthreads();

  // one point per lane: k = lane>>3, slot = lane&7: [c0..c3, g0,g1, l0,l1]
  int k = lane >> 3, s = lane & 7;
  int i, j;
  if (s < 4) {
    i = min(fl0s[k] + (s >> 1), T_ - 1);
    j = min(fl1s[k] + (s & 1), T_ - 1);
  } else if (s < 6) {
    uint32_t base = ((((uint32_t)blk) * 8u + (uint32_t)k) * 2u + (uint32_t)(s - 4)) * 2u;
    i = (int)(rand_bits32((uint32_t)KG_, (uint32_t)(KG_ >> 32), base + 0u) & 1023u);
    j = (int)(rand_bits32((uint32_t)KG_, (uint32_t)(KG_ >> 32), base + 1u) & 1023u);
  } else {
    uint32_t base = ((((uint32_t)blk) * 8u + (uint32_t)k) * 2u + (uint32_t)(s - 6)) * 2u;
    i = b0s[k] + (int)(rand_bits32((uint32_t)KN_, (uint32_t)(KN_ >> 32), base + 0u) & 1u);
    j = b1s[k] + (int)(rand_bits32((uint32_t)KN_, (uint32_t)(KN_ >> 32), base + 1u) & 1u);
  }
  if (j > i) { int tmp = i; i = j; j = tmp; }              // _flip on indices
  int code = (i << 10) | j;
  cs[lane] = code;
  __syncthreads();

  bool dup = false;
  for (int m = 0; m < lane; ++m) dup = dup || (cs[m] == code);

  float d[KMIX];
  float fi = (float)i, fj = (float)j;
#pragma unroll
  for (int kk = 0; kk < KMIX; ++kk) {
    float r0 = (fi - m0s[kk]) / sgs[kk];
    float r1 = (fj - m1s[kk]) / sgs[kk];
    d[kk] = dup ? 0.f : expf(-0.5f * (r0 * r0 + r1 * r1));
  }
  float w = 0.f;
#pragma unroll
  for (int kk = 0; kk < KMIX; ++kk) {
    float ssum = d[kk];
#pragma unroll
    for (int off = 32; off > 0; off >>= 1) ssum += __shfl_xor(ssum, off, 64);
    w += mvs[kk] * (d[kk] / ssum);
  }
  if (w != 0.f) {
    int key = ((blk >> 10) << 10) | i;    // b*1024 + i
    int pos = atomicAdd(&cnt[key], 1);
    if (pos < CAP) entries[(size_t)key * CAP + pos] = make_int2(j, __float_as_int(w));
  }
}

// ---------------- kernel 3: gather attention (quarter-wave: 16 lanes/entry, 2-way unroll) ----------------
// wave = head; 4 groups of 16 lanes process entries e ≡ g (mod 4); each lane covers 8 cols (bf16 uint4).
__global__ __launch_bounds__(512)
void gather_kernel(const int2* __restrict__ entries, const int* __restrict__ cnt,
                   const unsigned short* __restrict__ Qb, const unsigned short* __restrict__ Kb,
                   const unsigned short* __restrict__ Vb, float* __restrict__ att) {
  int bid = blockIdx.x;
  int key = ((bid & 7) << 8) | (bid >> 3);   // XCD swizzle: 2048 = 8 XCDs * 256 contiguous rows
  int b = key >> 10, i = key & 1023;
  int h = threadIdx.x >> 6, lane = threadIdx.x & 63;
  int g = lane >> 4, l4 = lane & 15;
  int n = min(cnt[key], CAP);
  const int2* ebase = entries + (size_t)key * CAP;

  const unsigned short* Qrow = Qb + (((size_t)b * H_ + h) * T_ + i) * E_;
  const unsigned short* Kh = Kb + ((size_t)b * H_ + h) * (size_t)T_ * E_;
  const unsigned short* Vh = Vb + ((size_t)b * H_ + h) * (size_t)T_ * E_;

  float q8[8];
  {
    uint4 qu = *(const uint4*)(Qrow + l4 * 8);
    bfpair(qu.x, q8[0], q8[1]); bfpair(qu.y, q8[2], q8[3]);
    bfpair(qu.z, q8[4], q8[5]); bfpair(qu.w, q8[6], q8[7]);
  }
  float acc8[8] = {};

  int e = g;
  // unrolled: two independent entries in flight per group
  for (; e + 4 < n; e += 8) {
    int2 ea = ebase[e];
    int2 eb = ebase[e + 4];
    uint4 ka = *(const uint4*)(Kh + (size_t)ea.x * E_ + l4 * 8);
    uint4 kb = *(const uint4*)(Kh + (size_t)eb.x * E_ + l4 * 8);
    uint4 va = *(const uint4*)(Vh + (size_t)ea.x * E_ + l4 * 8);
    uint4 vb = *(const uint4*)(Vh + (size_t)eb.x * E_ + l4 * 8);
    float f0, f1;
    float pa = 0.f, pb = 0.f;
    bfpair(ka.x, f0, f1); pa = fmaf(q8[0], f0, fmaf(q8[1], f1, pa));
    bfpair(ka.y, f0, f1); pa = fmaf(q8[2], f0, fmaf(q8[3], f1, pa));
    bfpair(ka.z, f0, f1); pa = fmaf(q8[4], f0, fmaf(q8[5], f1, pa));
    bfpair(ka.w, f0, f1); pa = fmaf(q8[6], f0, fmaf(q8[7], f1, pa));
    bfpair(kb.x, f0, f1); pb = fmaf(q8[0], f0, fmaf(q8[1], f1, pb));
    bfpair(kb.y, f0, f1); pb = fmaf(q8[2], f0, fmaf(q8[3], f1, pb));
    bfpair(kb.z, f0, f1); pb = fmaf(q8[4], f0, fmaf(q8[5], f1, pb));
    bfpair(kb.w, f0, f1); pb = fmaf(q8[6], f0, fmaf(q8[7], f1, pb));
    // two interleaved 4-step reduces within the 16-lane group
    pa += __shfl_xor(pa, 8, 64);  pb += __shfl_xor(pb, 8, 64);
    pa += __shfl_xor(pa, 4, 64);  pb += __shfl_xor(pb, 4, 64);
    pa += __shfl_xor(pa, 2, 64);  pb += __shfl_xor(pb, 2, 64);
    pa += __shfl_xor(pa, 1, 64);  pb += __shfl_xor(pb, 1, 64);
    float vala = pa * __int_as_float(ea.y);
    float valb = pb * __int_as_float(eb.y);
    float a0, a1;
    bfpair(va.x, f0, f1); bfpair(vb.x, a0, a1);
    acc8[0] = fmaf(vala, f0, fmaf(valb, a0, acc8[0]));
    acc8[1] = fmaf(vala, f1, fmaf(valb, a1, acc8[1]));
    bfpair(va.y, f0, f1); bfpair(vb.y, a0, a1);
    acc8[2] = fmaf(vala, f0, fmaf(valb, a0, acc8[2]));
    acc8[3] = fmaf(vala, f1, fmaf(valb, a1, acc8[3]));
    bfpair(va.z, f0, f1); bfpair(vb.z, a0, a1);
    acc8[4] = fmaf(vala, f0, fmaf(valb, a0, acc8[4]));
    acc8[5] = fmaf(vala, f1, fmaf(valb, a1, acc8[5]));
    bfpair(va.w, f0, f1); bfpair(vb.w, a0, a1);
    acc8[6] = fmaf(vala, f0, fmaf(valb, a0, acc8[6]));
    acc8[7] = fmaf(vala, f1, fmaf(valb, a1, acc8[7]));
  }
  // remainder: single entry per group per iteration
  for (; e < n; e += 4) {
    int2 ea = ebase[e];
    uint4 ka = *(const uint4*)(Kh + (size_t)ea.x * E_ + l4 * 8);
    uint4 va = *(const uint4*)(Vh + (size_t)ea.x * E_ + l4 * 8);
    float f0, f1;
    float pa = 0.f;
    bfpair(ka.x, f0, f1); pa = fmaf(q8[0], f0, fmaf(q8[1], f1, pa));
    bfpair(ka.y, f0, f1); pa = fmaf(q8[2], f0, fmaf(q8[3], f1, pa));
    bfpair(ka.z, f0, f1); pa = fmaf(q8[4], f0, fmaf(q8[5], f1, pa));
    bfpair(ka.w, f0, f1); pa = fmaf(q8[6], f0, fmaf(q8[7], f1, pa));
    pa += __shfl_xor(pa, 8, 64);
    pa += __shfl_xor(pa, 4, 64);
    pa += __shfl_xor(pa, 2, 64);
    pa += __shfl_xor(pa, 1, 64);
    float vala = pa * __int_as_float(ea.y);
    bfpair(va.x, f0, f1); acc8[0] = fmaf(vala, f0, acc8[0]); acc8[1] = fmaf(vala, f1, acc8[1]);
    bfpair(va.y, f0, f1); acc8[2] = fmaf(vala, f0, acc8[2]); acc8[3] = fmaf(vala, f1, acc8[3]);
    bfpair(va.z, f0, f1); acc8[4] = fmaf(vala, f0, acc8[4]); acc8[5] = fmaf(vala, f1, acc8[5]);
    bfpair(va.w, f0, f1); acc8[6] = fmaf(vala, f0, acc8[6]); acc8[7] = fmaf(vala, f1, acc8[7]);
  }
  // combine the 4 groups (same output cols per l4)
#pragma unroll
  for (int c = 0; c < 8; ++c) {
    acc8[c] += __shfl_xor(acc8[c], 16, 64);
    acc8[c] += __shfl_xor(acc8[c], 32, 64);
  }
  if (g == 0) {
    float* arow = att + (((size_t)b * H_ + h) * T_ + i) * E_ + l4 * 8;
    float4 s0 = {acc8[0], acc8[1], acc8[2], acc8[3]};
    float4 s1 = {acc8[4], acc8[5], acc8[6], acc8[7]};
    *(float4*)(arow + 0) = s0;
    *(float4*)(arow + 4) = s1;
  }
}

// ---------------- kernel 4: split-K output projection (z = head = K-chunk of 128) ----------------
__global__ __launch_bounds__(256)
void outproj_split_kernel(const float* __restrict__ att, const float* __restrict__ Wu,
                          float* __restrict__ partials) {
  __shared__ float As[64][68];   // [k][r] transposed
  __shared__ float Bs[64][68];
  int tid = threadIdx.x;
  int tm = tid >> 4, tn = tid & 15;
  int row0 = blockIdx.x * 64;   // rows = b*T + t
  int col0 = blockIdx.y * 64;   // 0 or 64
  int hh = blockIdx.z;          // head = K-chunk
  float acc[4][4] = {};
  for (int step = 0; step < 2; ++step) {
    int e0 = step * 64;
#pragma unroll
    for (int l = 0; l < 4; ++l) {
      int idx = tid + l * 256;
      int r = idx >> 4, c4 = idx & 15;
      int row = row0 + r;
      int bb = row >> 10, tt = row & 1023;
      float4 v = *(const float4*)(att + (((size_t)bb * H_ + hh) * T_ + tt) * E_ + e0 + c4 * 4);
      As[c4 * 4 + 0][r] = v.x; As[c4 * 4 + 1][r] = v.y;
      As[c4 * 4 + 2][r] = v.z; As[c4 * 4 + 3][r] = v.w;
    }
#pragma unroll
    for (int l = 0; l < 4; ++l) {
      int idx = tid + l * 256;
      int r = idx >> 4, c4 = idx & 15;
      float4 v = *(const float4*)(Wu + (size_t)(hh * 128 + e0 + r) * 128 + col0 + c4 * 4);
      Bs[r][c4 * 4 + 0] = v.x; Bs[r][c4 * 4 + 1] = v.y;
      Bs[r][c4 * 4 + 2] = v.z; Bs[r][c4 * 4 + 3] = v.w;
    }
    __syncthreads();
#pragma unroll 8
    for (int k2 = 0; k2 < 64; ++k2) {
      float4 a4 = *(const float4*)&As[k2][tm * 4];
      float4 b4 = *(const float4*)&Bs[k2][tn * 4];
      float av[4] = {a4.x, a4.y, a4.z, a4.w};
      float bv[4] = {b4.x, b4.y, b4.z, b4.w};
#pragma unroll
      for (int ii = 0; ii < 4; ++ii)
#pragma unroll
        for (int jj = 0; jj < 4; ++jj)
          acc[ii][jj] = fmaf(av[ii], bv[jj], acc[ii][jj]);
    }
    __syncthreads();
  }
  float* pbase = partials + (size_t)hh * NROWS * 128;
#pragma unroll
  for (int ii = 0; ii < 4; ++ii) {
    int row = row0 + tm * 4 + ii;
#pragma unroll
    for (int jj = 0; jj < 4; ++jj) {
      int col = col0 + tn * 4 + jj;
      pbase[(size_t)row * 128 + col] = acc[ii][jj];
    }
  }
}

// ---------------- kernel 5: reduce 8 partials + bias ----------------
__global__ __launch_bounds__(256)
void reduce_kernel(const float* __restrict__ partials, const float* __restrict__ bu,
                   float* __restrict__ out) {
  int idx = blockIdx.x * 256 + threadIdx.x;    // row*128 + col, 262144 total
  int col = idx & 127;
  float s = bu[col];
#pragma unroll
  for (int z = 0; z < H_; ++z)
    s += partials[(size_t)z * NROWS * 128 + idx];
  out[idx] = s;
}

extern "C" void kernel_launch(void* const* d_in, const int* in_sizes, int n_in,
                              void* d_out, int out_size, void* d_ws, size_t ws_size,
                              hipStream_t stream) {
  const float* x   = (const float*)d_in[0];
  const float* Wq  = (const float*)d_in[1];
  const float* Wk  = (const float*)d_in[2];
  const float* Wv  = (const float*)d_in[3];
  const float* Wu  = (const float*)d_in[4];
  const float* bu  = (const float*)d_in[5];
  const float* Wp1 = (const float*)d_in[6];
  const float* bp1 = (const float*)d_in[7];
  const float* Wp2 = (const float*)d_in[8];
  const float* bp2 = (const float*)d_in[9];
  const float* mv  = (const float*)d_in[10];
  float* out = (float*)d_out;

  const size_t NF = (size_t)B_ * H_ * T_ * E_;    // 2097152 elems per tensor
  unsigned short* Qb = (unsigned short*)d_ws;     // Q,K,V contiguous bf16: 12 MB
  unsigned short* Kb = Qb + NF;
  unsigned short* Vb = Kb + NF;
  float* att      = (float*)(Vb + NF);            // 8 MB fp32
  int*   cnt      = (int*)(att + NF);             // 2048 ints
  int2*  entries  = (int2*)(cnt + NROWS);         // 2048 * CAP * 8B = 5.24 MB
  float* partials = (float*)(entries + (size_t)NROWS * CAP);  // 8 MB

  const float scale = 0.29730177875068026f;       // 128^-0.25

  hipMemsetAsync(cnt, 0, NROWS * sizeof(int), stream);
  proj3_kernel<<<dim3(32, 16, 3), 256, 0, stream>>>(x, Wq, Wk, Wv, Qb, scale);
  token_kernel<<<NROWS, 64, 0, stream>>>(x, Wp1, bp1, Wp2, bp2, mv, entries, cnt);
  gather_kernel<<<NROWS, 512, 0, stream>>>(entries, cnt, Qb, Kb, Vb, att);
  outproj_split_kernel<<<dim3(32, 2, 8), 256, 0, stream>>>(att, Wu, partials);
  reduce_kernel<<<NROWS * 128 / 256, 256, 0, stream>>>(partials, bu, out);
}

// Round 17
// 131.622 us; speedup vs baseline: 2.8835x; 1.1032x over previous
//
#include <hip/hip_runtime.h>
#include <stdint.h>

#define B_ 2
#define T_ 1024
#define E_ 128
#define H_ 8
#define KMIX 8
#define NPTS_ 64
#define HID_ 64
#define NROWS (B_ * T_)              // 2048 row buckets
#define CAP 320                      // max entries per row bucket (audit: worst ~250)

typedef __bf16 bf16x8 __attribute__((ext_vector_type(8)));
typedef float  f32x4  __attribute__((ext_vector_type(4)));

// ---------------- bf16 helpers (RNE) ----------------
__device__ __forceinline__ unsigned short f2bf(float f) {
  uint32_t u = __float_as_uint(f);
  return (unsigned short)((u + 0x7FFFu + ((u >> 16) & 1u)) >> 16);
}
__device__ __forceinline__ float bf2f(unsigned short s) {
  return __uint_as_float(((uint32_t)s) << 16);
}
// unpack uint32 holding 2 bf16 -> 2 floats
__device__ __forceinline__ void bfpair(uint32_t u, float& lo, float& hi) {
  lo = __uint_as_float(u << 16);
  hi = __uint_as_float(u & 0xFFFF0000u);
}

// ---------------- threefry2x32 (JAX partitionable stream) ----------------
__device__ __forceinline__ void tf2x32(uint32_t k0, uint32_t k1,
                                       uint32_t x0, uint32_t x1,
                                       uint32_t& o0, uint32_t& o1) {
  uint32_t ks2 = k0 ^ k1 ^ 0x1BD11BDAu;
  x0 += k0; x1 += k1;
#define RND(r) { x0 += x1; x1 = (x1 << (r)) | (x1 >> (32 - (r))); x1 ^= x0; }
  RND(13) RND(15) RND(26) RND(6)
  x0 += k1;  x1 += ks2 + 1u;
  RND(17) RND(29) RND(16) RND(24)
  x0 += ks2; x1 += k0 + 2u;
  RND(13) RND(15) RND(26) RND(6)
  x0 += k0;  x1 += k1 + 3u;
  RND(17) RND(29) RND(16) RND(24)
  x0 += k1;  x1 += ks2 + 4u;
  RND(13) RND(15) RND(26) RND(6)
  x0 += ks2; x1 += k0 + 5u;
#undef RND
  o0 = x0; o1 = x1;
}

constexpr uint64_t tf_ce(uint32_t k0, uint32_t k1, uint32_t x0, uint32_t x1) {
  uint32_t ks2 = k0 ^ k1 ^ 0x1BD11BDAu;
  x0 += k0; x1 += k1;
#define RND(r) { x0 += x1; x1 = (x1 << (r)) | (x1 >> (32 - (r))); x1 ^= x0; }
  RND(13) RND(15) RND(26) RND(6)
  x0 += k1;  x1 += ks2 + 1u;
  RND(17) RND(29) RND(16) RND(24)
  x0 += ks2; x1 += k0 + 2u;
  RND(13) RND(15) RND(26) RND(6)
  x0 += k0;  x1 += k1 + 3u;
  RND(17) RND(29) RND(16) RND(24)
  x0 += k1;  x1 += ks2 + 4u;
  RND(13) RND(15) RND(26) RND(6)
  x0 += ks2; x1 += k0 + 5u;
#undef RND
  return ((uint64_t)x1 << 32) | x0;
}
constexpr uint64_t lower_key_ce(uint32_t which) {
  uint64_t a = tf_ce(0u, 1u, 0u, which);                       // split(key(1))[which]
  return tf_ce((uint32_t)a, (uint32_t)(a >> 32), 0u, 1u);      // split(that)[1]
}
constexpr uint64_t KG_ = lower_key_ce(0);   // glob randint lower key
constexpr uint64_t KN_ = lower_key_ce(1);   // loc randint lower key

__device__ __forceinline__ uint32_t rand_bits32(uint32_t k0, uint32_t k1, uint32_t f) {
  uint32_t o0, o1;
  tf2x32(k0, k1, 0u, f, o0, o1);
  return o0 ^ o1;                           // partitionable 32-bit draw
}

// ---------------- kernel 1: fused Q/K/V projection via bf16 MFMA ----------------
// C = x(2048x128) @ W(128x1024); z selects {Wq,Wk,Wv}; out bf16 permuted [b][h][t][e].
// Block: 64x64 tile, 4 waves (wave = 16 rows). LDS: x-tile bf16 [64][128+8], W^T bf16 [64][128+8].
__global__ __launch_bounds__(256)
void proj3_kernel(const float* __restrict__ A,
                  const float* __restrict__ Wq, const float* __restrict__ Wk,
                  const float* __restrict__ Wv,
                  unsigned short* __restrict__ outbase, float scale) {
  const float* W = (blockIdx.z == 0) ? Wq : (blockIdx.z == 1) ? Wk : Wv;
  float sc = (blockIdx.z == 2) ? 1.0f : scale;
  unsigned short* out = outbase + (size_t)blockIdx.z * (size_t)B_ * H_ * T_ * E_;

  __shared__ alignas(16) unsigned short Axs[64][136];   // [row][k], +8 pad -> 2-way-free b128 reads
  __shared__ alignas(16) unsigned short WT[64][136];    // [n][k] transposed

  int tid = threadIdx.x;
  int row0 = blockIdx.x * 64;
  int col0 = blockIdx.y * 64;

  // stage x tile: 64 rows x 128 cols fp32 -> bf16
#pragma unroll
  for (int l = 0; l < 8; ++l) {
    int idx = tid + l * 256;          // 2048 float4-slots
    int r = idx >> 5, c4 = idx & 31;
    float4 v = *(const float4*)(A + (size_t)(row0 + r) * 128 + c4 * 4);
    ushort4 st = {f2bf(v.x), f2bf(v.y), f2bf(v.z), f2bf(v.w)};
    *(ushort4*)&Axs[r][c4 * 4] = st;
  }
  // stage W tile transposed: 128k x 64n fp32 -> WT[n][k] bf16 (4x4 blocked)
#pragma unroll
  for (int half = 0; half < 2; ++half) {
    int tau = tid + half * 256;       // 512 4x4 tiles
    int kb = tau >> 4, nb = tau & 15;
    float4 v0 = *(const float4*)(W + (size_t)(kb * 4 + 0) * 1024 + col0 + nb * 4);
    float4 v1 = *(const float4*)(W + (size_t)(kb * 4 + 1) * 1024 + col0 + nb * 4);
    float4 v2 = *(const float4*)(W + (size_t)(kb * 4 + 2) * 1024 + col0 + nb * 4);
    float4 v3 = *(const float4*)(W + (size_t)(kb * 4 + 3) * 1024 + col0 + nb * 4);
    ushort4 w0 = {f2bf(v0.x), f2bf(v1.x), f2bf(v2.x), f2bf(v3.x)};
    ushort4 w1 = {f2bf(v0.y), f2bf(v1.y), f2bf(v2.y), f2bf(v3.y)};
    ushort4 w2 = {f2bf(v0.z), f2bf(v1.z), f2bf(v2.z), f2bf(v3.z)};
    ushort4 w3 = {f2bf(v0.w), f2bf(v1.w), f2bf(v2.w), f2bf(v3.w)};
    *(ushort4*)&WT[nb * 4 + 0][kb * 4] = w0;
    *(ushort4*)&WT[nb * 4 + 1][kb * 4] = w1;
    *(ushort4*)&WT[nb * 4 + 2][kb * 4] = w2;
    *(ushort4*)&WT[nb * 4 + 3][kb * 4] = w3;
  }
  __syncthreads();

  int w = tid >> 6, l = tid & 63;
  int l15 = l & 15, lh = l >> 4;
  int arow = w * 16 + l15;

  f32x4 acc[4] = {f32x4{0.f,0.f,0.f,0.f}, f32x4{0.f,0.f,0.f,0.f},
                  f32x4{0.f,0.f,0.f,0.f}, f32x4{0.f,0.f,0.f,0.f}};
#pragma unroll
  for (int kt = 0; kt < 4; ++kt) {
    uint4 au = *(const uint4*)&Axs[arow][kt * 32 + lh * 8];
    bf16x8 afrag = __builtin_bit_cast(bf16x8, au);
#pragma unroll
    for (int nt = 0; nt < 4; ++nt) {
      uint4 bu = *(const uint4*)&WT[nt * 16 + l15][kt * 32 + lh * 8];
      bf16x8 bfrag = __builtin_bit_cast(bf16x8, bu);
      acc[nt] = __builtin_amdgcn_mfma_f32_16x16x32_bf16(afrag, bfrag, acc[nt], 0, 0, 0);
    }
  }
  // epilogue: C/D layout col=lane&15, row=(lane>>4)*4+reg  [m89-verified]
#pragma unroll
  for (int nt = 0; nt < 4; ++nt) {
    int col = col0 + nt * 16 + l15;
    int hh = col >> 7, ee = col & 127;
#pragma unroll
    for (int reg = 0; reg < 4; ++reg) {
      int m = row0 + w * 16 + lh * 4 + reg;
      int bb = m >> 10, tt = m & 1023;
      out[(((size_t)bb * H_ + hh) * T_ + tt) * E_ + ee] = f2bf(acc[nt][reg] * sc);
    }
  }
}

// ---------------- kernel 2: per-token hypernet + points + direct bucketed entries ----------------
__global__ __launch_bounds__(64)
void token_kernel(const float* __restrict__ x,
                  const float* __restrict__ Wp1, const float* __restrict__ bp1,
                  const float* __restrict__ Wp2, const float* __restrict__ bp2,
                  const float* __restrict__ mv,
                  int2* __restrict__ entries, int* __restrict__ cnt) {
  int blk = blockIdx.x;            // b*T + t
  int t = blk & 1023;
  int lane = threadIdx.x;

  __shared__ float xs[E_];
  __shared__ float hs[HID_];
  __shared__ float ps[24];
  __shared__ float m0s[KMIX], m1s[KMIX], sgs[KMIX];
  __shared__ int   fl0s[KMIX], fl1s[KMIX], b0s[KMIX], b1s[KMIX];
  __shared__ int   cs[NPTS_];
  __shared__ float mvs[KMIX];

  xs[lane]      = x[(size_t)blk * E_ + lane];
  xs[lane + 64] = x[(size_t)blk * E_ + lane + 64];
  if (lane < KMIX) mvs[lane] = mv[lane];
  __syncthreads();

  {
    float acc = bp1[lane];
    for (int c = 0; c < E_; ++c) acc = fmaf(xs[c], Wp1[c * HID_ + lane], acc);
    hs[lane] = fmaxf(acc, 0.f);
  }
  __syncthreads();

  if (lane < 24) {
    float p = bp2[lane];
    for (int jj = 0; jj < HID_; ++jj) p = fmaf(hs[jj], Wp2[jj * 24 + lane], p);
    ps[lane] = p;
  }
  __syncthreads();

  if (lane < KMIX) {
    float m0 = ps[2 * lane] + (float)t;
    float m1 = ps[2 * lane + 1] + (float)t;
    if (m1 > m0) { float tmp = m0; m0 = m1; m1 = tmp; }   // _flip
    m0 = fminf(fmaxf(m0, 0.f), (float)(T_ - 1));
    m1 = fminf(fmaxf(m1, 0.f), (float)(T_ - 1));
    float sr = ps[16 + lane] + 2.0f;                       // SIGMA_BOOST
    float sig = fmaxf(sr, 0.f) + log1pf(expf(-fabsf(sr))) + 0.01f;  // softplus + MIN_SIGMA
    m0s[lane] = m0; m1s[lane] = m1; sgs[lane] = sig;
    int f0 = (int)floorf(m0), f1 = (int)floorf(m1);
    fl0s[lane] = f0; fl1s[lane] = f1;
    b0s[lane] = min(max(f0 - 1, 0), T_ - 2);
    b1s[lane] = min(max(f1 - 1, 0), T_ - 2);
  }
  __syncthreads();

  // one point per lane: k = lane>>3, slot = lane&7: [c0..c3, g0,g1, l0,l1]
  int k = lane >> 3, s = lane & 7;
  int i, j;
  if (s < 4) {
    i = min(fl0s[k] + (s >> 1), T_ - 1);
    j = min(fl1s[k] + (s & 1), T_ - 1);
  } else if (s < 6) {
    uint32_t base = ((((uint32_t)blk) * 8u + (uint32_t)k) * 2u + (uint32_t)(s - 4)) * 2u;
    i = (int)(rand_bits32((uint32_t)KG_, (uint32_t)(KG_ >> 32), base + 0u) & 1023u);
    j = (int)(rand_bits32((uint32_t)KG_, (uint32_t)(KG_ >> 32), base + 1u) & 1023u);
  } else {
    uint32_t base = ((((uint32_t)blk) * 8u + (uint32_t)k) * 2u + (uint32_t)(s - 6)) * 2u;
    i = b0s[k] + (int)(rand_bits32((uint32_t)KN_, (uint32_t)(KN_ >> 32), base + 0u) & 1u);
    j = b1s[k] + (int)(rand_bits32((uint32_t)KN_, (uint32_t)(KN_ >> 32), base + 1u) & 1u);
  }
  if (j > i) { int tmp = i; i = j; j = tmp; }              // _flip on indices
  int code = (i << 10) | j;
  cs[lane] = code;
  __syncthreads();

  bool dup = false;
  for (int m = 0; m < lane; ++m) dup = dup || (cs[m] == code);

  float d[KMIX];
  float fi = (float)i, fj = (float)j;
#pragma unroll
  for (int kk = 0; kk < KMIX; ++kk) {
    float r0 = (fi - m0s[kk]) / sgs[kk];
    float r1 = (fj - m1s[kk]) / sgs[kk];
    d[kk] = dup ? 0.f : expf(-0.5f * (r0 * r0 + r1 * r1));
  }
  float w = 0.f;
#pragma unroll
  for (int kk = 0; kk < KMIX; ++kk) {
    float ssum = d[kk];
#pragma unroll
    for (int off = 32; off > 0; off >>= 1) ssum += __shfl_xor(ssum, off, 64);
    w += mvs[kk] * (d[kk] / ssum);
  }
  if (w != 0.f) {
    int key = ((blk >> 10) << 10) | i;    // b*1024 + i
    int pos = atomicAdd(&cnt[key], 1);
    if (pos < CAP) entries[(size_t)key * CAP + pos] = make_int2(j, __float_as_int(w));
  }
}

// ---------------- kernel 3: gather attention (quarter-wave: 16 lanes/entry, 2-way unroll) ----------------
__global__ __launch_bounds__(512)
void gather_kernel(const int2* __restrict__ entries, const int* __restrict__ cnt,
                   const unsigned short* __restrict__ Qb, const unsigned short* __restrict__ Kb,
                   const unsigned short* __restrict__ Vb, float* __restrict__ att) {
  int bid = blockIdx.x;
  int key = ((bid & 7) << 8) | (bid >> 3);   // XCD swizzle
  int b = key >> 10, i = key & 1023;
  int h = threadIdx.x >> 6, lane = threadIdx.x & 63;
  int g = lane >> 4, l4 = lane & 15;
  int n = min(cnt[key], CAP);
  const int2* ebase = entries + (size_t)key * CAP;

  const unsigned short* Qrow = Qb + (((size_t)b * H_ + h) * T_ + i) * E_;
  const unsigned short* Kh = Kb + ((size_t)b * H_ + h) * (size_t)T_ * E_;
  const unsigned short* Vh = Vb + ((size_t)b * H_ + h) * (size_t)T_ * E_;

  float q8[8];
  {
    uint4 qu = *(const uint4*)(Qrow + l4 * 8);
    bfpair(qu.x, q8[0], q8[1]); bfpair(qu.y, q8[2], q8[3]);
    bfpair(qu.z, q8[4], q8[5]); bfpair(qu.w, q8[6], q8[7]);
  }
  float acc8[8] = {};

  int e = g;
  for (; e + 4 < n; e += 8) {
    int2 ea = ebase[e];
    int2 eb = ebase[e + 4];
    uint4 ka = *(const uint4*)(Kh + (size_t)ea.x * E_ + l4 * 8);
    uint4 kb = *(const uint4*)(Kh + (size_t)eb.x * E_ + l4 * 8);
    uint4 va = *(const uint4*)(Vh + (size_t)ea.x * E_ + l4 * 8);
    uint4 vb = *(const uint4*)(Vh + (size_t)eb.x * E_ + l4 * 8);
    float f0, f1;
    float pa = 0.f, pb = 0.f;
    bfpair(ka.x, f0, f1); pa = fmaf(q8[0], f0, fmaf(q8[1], f1, pa));
    bfpair(ka.y, f0, f1); pa = fmaf(q8[2], f0, fmaf(q8[3], f1, pa));
    bfpair(ka.z, f0, f1); pa = fmaf(q8[4], f0, fmaf(q8[5], f1, pa));
    bfpair(ka.w, f0, f1); pa = fmaf(q8[6], f0, fmaf(q8[7], f1, pa));
    bfpair(kb.x, f0, f1); pb = fmaf(q8[0], f0, fmaf(q8[1], f1, pb));
    bfpair(kb.y, f0, f1); pb = fmaf(q8[2], f0, fmaf(q8[3], f1, pb));
    bfpair(kb.z, f0, f1); pb = fmaf(q8[4], f0, fmaf(q8[5], f1, pb));
    bfpair(kb.w, f0, f1); pb = fmaf(q8[6], f0, fmaf(q8[7], f1, pb));
    pa += __shfl_xor(pa, 8, 64);  pb += __shfl_xor(pb, 8, 64);
    pa += __shfl_xor(pa, 4, 64);  pb += __shfl_xor(pb, 4, 64);
    pa += __shfl_xor(pa, 2, 64);  pb += __shfl_xor(pb, 2, 64);
    pa += __shfl_xor(pa, 1, 64);  pb += __shfl_xor(pb, 1, 64);
    float vala = pa * __int_as_float(ea.y);
    float valb = pb * __int_as_float(eb.y);
    float a0, a1;
    bfpair(va.x, f0, f1); bfpair(vb.x, a0, a1);
    acc8[0] = fmaf(vala, f0, fmaf(valb, a0, acc8[0]));
    acc8[1] = fmaf(vala, f1, fmaf(valb, a1, acc8[1]));
    bfpair(va.y, f0, f1); bfpair(vb.y, a0, a1);
    acc8[2] = fmaf(vala, f0, fmaf(valb, a0, acc8[2]));
    acc8[3] = fmaf(vala, f1, fmaf(valb, a1, acc8[3]));
    bfpair(va.z, f0, f1); bfpair(vb.z, a0, a1);
    acc8[4] = fmaf(vala, f0, fmaf(valb, a0, acc8[4]));
    acc8[5] = fmaf(vala, f1, fmaf(valb, a1, acc8[5]));
    bfpair(va.w, f0, f1); bfpair(vb.w, a0, a1);
    acc8[6] = fmaf(vala, f0, fmaf(valb, a0, acc8[6]));
    acc8[7] = fmaf(vala, f1, fmaf(valb, a1, acc8[7]));
  }
  for (; e < n; e += 4) {
    int2 ea = ebase[e];
    uint4 ka = *(const uint4*)(Kh + (size_t)ea.x * E_ + l4 * 8);
    uint4 va = *(const uint4*)(Vh + (size_t)ea.x * E_ + l4 * 8);
    float f0, f1;
    float pa = 0.f;
    bfpair(ka.x, f0, f1); pa = fmaf(q8[0], f0, fmaf(q8[1], f1, pa));
    bfpair(ka.y, f0, f1); pa = fmaf(q8[2], f0, fmaf(q8[3], f1, pa));
    bfpair(ka.z, f0, f1); pa = fmaf(q8[4], f0, fmaf(q8[5], f1, pa));
    bfpair(ka.w, f0, f1); pa = fmaf(q8[6], f0, fmaf(q8[7], f1, pa));
    pa += __shfl_xor(pa, 8, 64);
    pa += __shfl_xor(pa, 4, 64);
    pa += __shfl_xor(pa, 2, 64);
    pa += __shfl_xor(pa, 1, 64);
    float vala = pa * __int_as_float(ea.y);
    bfpair(va.x, f0, f1); acc8[0] = fmaf(vala, f0, acc8[0]); acc8[1] = fmaf(vala, f1, acc8[1]);
    bfpair(va.y, f0, f1); acc8[2] = fmaf(vala, f0, acc8[2]); acc8[3] = fmaf(vala, f1, acc8[3]);
    bfpair(va.z, f0, f1); acc8[4] = fmaf(vala, f0, acc8[4]); acc8[5] = fmaf(vala, f1, acc8[5]);
    bfpair(va.w, f0, f1); acc8[6] = fmaf(vala, f0, acc8[6]); acc8[7] = fmaf(vala, f1, acc8[7]);
  }
#pragma unroll
  for (int c = 0; c < 8; ++c) {
    acc8[c] += __shfl_xor(acc8[c], 16, 64);
    acc8[c] += __shfl_xor(acc8[c], 32, 64);
  }
  if (g == 0) {
    float* arow = att + (((size_t)b * H_ + h) * T_ + i) * E_ + l4 * 8;
    float4 s0 = {acc8[0], acc8[1], acc8[2], acc8[3]};
    float4 s1 = {acc8[4], acc8[5], acc8[6], acc8[7]};
    *(float4*)(arow + 0) = s0;
    *(float4*)(arow + 4) = s1;
  }
}

// ---------------- kernel 4: split-K output projection (z = head = K-chunk of 128) ----------------
__global__ __launch_bounds__(256)
void outproj_split_kernel(const float* __restrict__ att, const float* __restrict__ Wu,
                          float* __restrict__ partials) {
  __shared__ float As[64][68];   // [k][r] transposed
  __shared__ float Bs[64][68];
  int tid = threadIdx.x;
  int tm = tid >> 4, tn = tid & 15;
  int row0 = blockIdx.x * 64;   // rows = b*T + t
  int col0 = blockIdx.y * 64;   // 0 or 64
  int hh = blockIdx.z;          // head = K-chunk
  float acc[4][4] = {};
  for (int step = 0; step < 2; ++step) {
    int e0 = step * 64;
#pragma unroll
    for (int l = 0; l < 4; ++l) {
      int idx = tid + l * 256;
      int r = idx >> 4, c4 = idx & 15;
      int row = row0 + r;
      int bb = row >> 10, tt = row & 1023;
      float4 v = *(const float4*)(att + (((size_t)bb * H_ + hh) * T_ + tt) * E_ + e0 + c4 * 4);
      As[c4 * 4 + 0][r] = v.x; As[c4 * 4 + 1][r] = v.y;
      As[c4 * 4 + 2][r] = v.z; As[c4 * 4 + 3][r] = v.w;
    }
#pragma unroll
    for (int l = 0; l < 4; ++l) {
      int idx = tid + l * 256;
      int r = idx >> 4, c4 = idx & 15;
      float4 v = *(const float4*)(Wu + (size_t)(hh * 128 + e0 + r) * 128 + col0 + c4 * 4);
      Bs[r][c4 * 4 + 0] = v.x; Bs[r][c4 * 4 + 1] = v.y;
      Bs[r][c4 * 4 + 2] = v.z; Bs[r][c4 * 4 + 3] = v.w;
    }
    __syncthreads();
#pragma unroll 8
    for (int k2 = 0; k2 < 64; ++k2) {
      float4 a4 = *(const float4*)&As[k2][tm * 4];
      float4 b4 = *(const float4*)&Bs[k2][tn * 4];
      float av[4] = {a4.x, a4.y, a4.z, a4.w};
      float bv[4] = {b4.x, b4.y, b4.z, b4.w};
#pragma unroll
      for (int ii = 0; ii < 4; ++ii)
#pragma unroll
        for (int jj = 0; jj < 4; ++jj)
          acc[ii][jj] = fmaf(av[ii], bv[jj], acc[ii][jj]);
    }
    __syncthreads();
  }
  float* pbase = partials + (size_t)hh * NROWS * 128;
#pragma unroll
  for (int ii = 0; ii < 4; ++ii) {
    int row = row0 + tm * 4 + ii;
#pragma unroll
    for (int jj = 0; jj < 4; ++jj) {
      int col = col0 + tn * 4 + jj;
      pbase[(size_t)row * 128 + col] = acc[ii][jj];
    }
  }
}

// ---------------- kernel 5: reduce 8 partials + bias ----------------
__global__ __launch_bounds__(256)
void reduce_kernel(const float* __restrict__ partials, const float* __restrict__ bu,
                   float* __restrict__ out) {
  int idx = blockIdx.x * 256 + threadIdx.x;    // row*128 + col, 262144 total
  int col = idx & 127;
  float s = bu[col];
#pragma unroll
  for (int z = 0; z < H_; ++z)
    s += partials[(size_t)z * NROWS * 128 + idx];
  out[idx] = s;
}

extern "C" void kernel_launch(void* const* d_in, const int* in_sizes, int n_in,
                              void* d_out, int out_size, void* d_ws, size_t ws_size,
                              hipStream_t stream) {
  const float* x   = (const float*)d_in[0];
  const float* Wq  = (const float*)d_in[1];
  const float* Wk  = (const float*)d_in[2];
  const float* Wv  = (const float*)d_in[3];
  const float* Wu  = (const float*)d_in[4];
  const float* bu  = (const float*)d_in[5];
  const float* Wp1 = (const float*)d_in[6];
  const float* bp1 = (const float*)d_in[7];
  const float* Wp2 = (const float*)d_in[8];
  const float* bp2 = (const float*)d_in[9];
  const float* mv  = (const float*)d_in[10];
  float* out = (float*)d_out;

  const size_t NF = (size_t)B_ * H_ * T_ * E_;    // 2097152 elems per tensor
  unsigned short* Qb = (unsigned short*)d_ws;     // Q,K,V contiguous bf16: 12 MB
  unsigned short* Kb = Qb + NF;
  unsigned short* Vb = Kb + NF;
  float* att      = (float*)(Vb + NF);            // 8 MB fp32
  int*   cnt      = (int*)(att + NF);             // 2048 ints
  int2*  entries  = (int2*)(cnt + NROWS);         // 2048 * CAP * 8B = 5.24 MB
  float* partials = (float*)(entries + (size_t)NROWS * CAP);  // 8 MB

  const float scale = 0.29730177875068026f;       // 128^-0.25

  hipMemsetAsync(cnt, 0, NROWS * sizeof(int), stream);
  proj3_kernel<<<dim3(32, 16, 3), 256, 0, stream>>>(x, Wq, Wk, Wv, Qb, scale);
  token_kernel<<<NROWS, 64, 0, stream>>>(x, Wp1, bp1, Wp2, bp2, mv, entries, cnt);
  gather_kernel<<<NROWS, 512, 0, stream>>>(entries, cnt, Qb, Kb, Vb, att);
  outproj_split_kernel<<<dim3(32, 2, 8), 256, 0, stream>>>(att, Wu, partials);
  reduce_kernel<<<NROWS * 128 / 256, 256, 0, stream>>>(partials, bu, out);
}